// Round 1
// baseline (4455.748 us; speedup 1.0000x reference)
//
#include <hip/hip_runtime.h>

#define N_TOK 16384
#define KCB   16384
#define DIM   256
#define HW    1024
#define DECAYF 0.8f
#define ONE_M_DECAY 0.2f
#define BETAF 0.25f
#define EPSF  1e-5f

// ---------------- ws layout (float elements) ----------------
// zf:     [0,        4194304)   z transposed to [n][d]
// pmin:   [4194304,  4259840)   N*4 partial mins
// pidx:   [4259840,  4325376)   N*4 partial argmins (int)
// token:  [4325376,  4341760)   N (int)
// counts: [4341760,  4358144)   K   (zeroed each launch)
// scal:   [4358144,  4358160)   [sumsq, n_tot, used, plogp] (zeroed)
// wnorm:  [4358160,  4374544)   K
// total ~17.5 MB

__device__ __forceinline__ float wave_reduce_sum(float s) {
    #pragma unroll
    for (int o = 32; o > 0; o >>= 1) s += __shfl_down(s, o);
    return s;
}

// ---- K1: transpose z[b][c][hw] -> zf[b*HW+hw][c] ----
__global__ void k_transpose_z(const float* __restrict__ z, float* __restrict__ zf) {
    __shared__ float t[32][33];
    int b  = blockIdx.z;
    int c0 = blockIdx.y * 32;
    int h0 = blockIdx.x * 32;
    int tid = threadIdx.x;
    int jx = tid & 31, iy = tid >> 5;               // iy in [0,8)
    const float* zb = z + (size_t)b * DIM * HW;
    #pragma unroll
    for (int p = 0; p < 4; ++p) {
        int ci = iy + p * 8;
        t[ci][jx] = zb[(size_t)(c0 + ci) * HW + h0 + jx];
    }
    __syncthreads();
    float* zfb = zf + (size_t)b * HW * DIM;
    #pragma unroll
    for (int p = 0; p < 4; ++p) {
        int hh = iy + p * 8;
        zfb[(size_t)(h0 + hh) * DIM + c0 + jx] = t[jx][hh];
    }
}

// ---- K2: wnorm[k] = |w_k|^2, one wave per row ----
__global__ void k_wnorm(const float* __restrict__ w, float* __restrict__ wnorm) {
    int wave = blockIdx.x * 4 + (threadIdx.x >> 6);
    int lane = threadIdx.x & 63;
    float4 v = ((const float4*)(w + (size_t)wave * DIM))[lane];
    float s = v.x * v.x + v.y * v.y + v.z * v.z + v.w * v.w;
    s = wave_reduce_sum(s);
    if (lane == 0) wnorm[wave] = s;
}

// ---- K3: distance GEMM + per-chunk argmin ----
// grid (256 n-tiles, 4 k-chunks), 256 threads. Tile 64n x 64k, full-D A in LDS.
#define SA 260
__global__ __launch_bounds__(256, 2) void k_dist(const float* __restrict__ zf,
                                                 const float* __restrict__ w,
                                                 const float* __restrict__ wnorm,
                                                 float* __restrict__ pmin,
                                                 int* __restrict__ pidx) {
    __shared__ float As[64][SA];
    __shared__ float Bs[64][36];
    int tid = threadIdx.x;
    int tx = tid & 15, ty = tid >> 4;
    int n0 = blockIdx.x * 64;
    int kc = blockIdx.y;

    // stage A tile: zf rows n0..n0+63, all 256 d (coalesced float4)
    #pragma unroll
    for (int i = 0; i < 16; ++i) {
        int lin = tid + i * 256;                 // float4 index over 64x64
        int r = lin >> 6, c4 = lin & 63;
        float4 v = ((const float4*)zf)[(size_t)(n0 + r) * 64 + c4];
        *(float4*)&As[r][c4 * 4] = v;
    }

    float minv[4] = {1e30f, 1e30f, 1e30f, 1e30f};
    int   mini[4] = {0, 0, 0, 0};

    for (int kt = 0; kt < 64; ++kt) {
        int k0 = kc * 4096 + kt * 64;
        float acc[4][4] = {{0.f,0.f,0.f,0.f},{0.f,0.f,0.f,0.f},
                           {0.f,0.f,0.f,0.f},{0.f,0.f,0.f,0.f}};
        for (int dc = 0; dc < DIM; dc += 32) {
            __syncthreads();
            #pragma unroll
            for (int i = 0; i < 2; ++i) {
                int lin = tid + i * 256;         // float4 over 64k x 8
                int r = lin >> 3, c4 = lin & 7;
                float4 v = ((const float4*)w)[(size_t)(k0 + r) * 64 + (dc >> 2) + c4];
                *(float4*)&Bs[r][c4 * 4] = v;
            }
            __syncthreads();
            #pragma unroll
            for (int dg = 0; dg < 8; ++dg) {
                float4 a0 = *(const float4*)&As[ty +  0][dc + dg * 4];
                float4 a1 = *(const float4*)&As[ty + 16][dc + dg * 4];
                float4 a2 = *(const float4*)&As[ty + 32][dc + dg * 4];
                float4 a3 = *(const float4*)&As[ty + 48][dc + dg * 4];
                float4 b0 = *(const float4*)&Bs[tx +  0][dg * 4];
                float4 b1 = *(const float4*)&Bs[tx + 16][dg * 4];
                float4 b2 = *(const float4*)&Bs[tx + 32][dg * 4];
                float4 b3 = *(const float4*)&Bs[tx + 48][dg * 4];
                #define MAC(rr, aa) \
                    acc[rr][0] += aa.x*b0.x + aa.y*b0.y + aa.z*b0.z + aa.w*b0.w; \
                    acc[rr][1] += aa.x*b1.x + aa.y*b1.y + aa.z*b1.z + aa.w*b1.w; \
                    acc[rr][2] += aa.x*b2.x + aa.y*b2.y + aa.z*b2.z + aa.w*b2.w; \
                    acc[rr][3] += aa.x*b3.x + aa.y*b3.y + aa.z*b3.z + aa.w*b3.w;
                MAC(0, a0) MAC(1, a1) MAC(2, a2) MAC(3, a3)
                #undef MAC
            }
        }
        // epilogue: score = |w|^2 - 2 z.w  (|z|^2 dropped: argmin-invariant)
        #pragma unroll
        for (int cc = 0; cc < 4; ++cc) {
            int kk = k0 + tx + 16 * cc;
            float wn = wnorm[kk];
            #pragma unroll
            for (int rr = 0; rr < 4; ++rr) {
                float s = wn - 2.0f * acc[rr][cc];
                if (s < minv[rr]) { minv[rr] = s; mini[rr] = kk; }
            }
        }
    }

    // block reduce across tx (16 partials per row); alias onto Bs (2304 floats)
    __syncthreads();
    float* smin = &Bs[0][0];                  // 1024 floats
    int*   sidx = (int*)(&Bs[0][0] + 1024);   // 1024 ints
    #pragma unroll
    for (int rr = 0; rr < 4; ++rr) {
        smin[(ty + 16 * rr) * 16 + tx] = minv[rr];
        sidx[(ty + 16 * rr) * 16 + tx] = mini[rr];
    }
    __syncthreads();
    if (tid < 64) {
        float bv = smin[tid * 16];
        int   bi = sidx[tid * 16];
        #pragma unroll
        for (int t = 1; t < 16; ++t) {
            float v = smin[tid * 16 + t];
            int  ii = sidx[tid * 16 + t];
            if (v < bv || (v == bv && ii < bi)) { bv = v; bi = ii; }
        }
        pmin[(size_t)(n0 + tid) * 4 + kc] = bv;
        pidx[(n0 + tid) * 4 + kc] = bi;
    }
}

// ---- K4: reduce 4 chunks -> token[n] ----
__global__ void k_token(const float* __restrict__ pmin, const int* __restrict__ pidx,
                        int* __restrict__ token) {
    int n = blockIdx.x * 256 + threadIdx.x;
    float bv = pmin[n * 4];
    int   bi = pidx[n * 4];
    #pragma unroll
    for (int c = 1; c < 4; ++c) {
        float v = pmin[n * 4 + c];
        int  ii = pidx[n * 4 + c];
        if (v < bv || (v == bv && ii < bi)) { bv = v; bi = ii; }
    }
    token[n] = bi;
}

// ---- K_init: embed_avg_new = DECAY * embed_avg ----
__global__ void k_init_embed(const float* __restrict__ ea, float* __restrict__ o_embed) {
    int i = blockIdx.x * 256 + threadIdx.x;
    float4 v = ((const float4*)ea)[i];
    ((float4*)o_embed)[i] = make_float4(DECAYF * v.x, DECAYF * v.y, DECAYF * v.z, DECAYF * v.w);
}

// ---- K5: per-token gather + scatter (sumsq, counts, embed_sum) ----
__global__ void k_gather(const int* __restrict__ token, const float* __restrict__ zf,
                         const float* __restrict__ w, float* __restrict__ counts,
                         float* __restrict__ o_embed, float* __restrict__ scal) {
    int n = blockIdx.x * 4 + (threadIdx.x >> 6);
    int lane = threadIdx.x & 63;
    int t = token[n];
    float4 wv = ((const float4*)(w  + (size_t)t * DIM))[lane];
    float4 zv = ((const float4*)(zf + (size_t)n * DIM))[lane];
    float dx = wv.x - zv.x, dy = wv.y - zv.y, dz = wv.z - zv.z, dw = wv.w - zv.w;
    float s = dx * dx + dy * dy + dz * dz + dw * dw;
    s = wave_reduce_sum(s);
    if (lane == 0) {
        atomicAdd(&scal[0], s);
        atomicAdd(&counts[t], 1.0f);
    }
    float* ed = o_embed + (size_t)t * DIM + lane * 4;
    atomicAdd(ed + 0, ONE_M_DECAY * zv.x);
    atomicAdd(ed + 1, ONE_M_DECAY * zv.y);
    atomicAdd(ed + 2, ONE_M_DECAY * zv.z);
    atomicAdd(ed + 3, ONE_M_DECAY * zv.w);
}

// ---- K6: out[b][c][hw] = weight[token[b*HW+hw]][c]  (gather + tile transpose) ----
__global__ void k_write_out(const int* __restrict__ token, const float* __restrict__ w,
                            float* __restrict__ out) {
    __shared__ float t[32][33];
    __shared__ int tok[32];
    int b = blockIdx.z, c0 = blockIdx.y * 32, h0 = blockIdx.x * 32;
    int tid = threadIdx.x, jx = tid & 31, iy = tid >> 5;
    if (tid < 32) tok[tid] = token[b * HW + h0 + tid];
    __syncthreads();
    #pragma unroll
    for (int p = 0; p < 4; ++p) {
        int hh = iy + p * 8;
        t[hh][jx] = w[(size_t)tok[hh] * DIM + c0 + jx];
    }
    __syncthreads();
    #pragma unroll
    for (int p = 0; p < 4; ++p) {
        int cc = iy + p * 8;
        out[(size_t)b * DIM * HW + (size_t)(c0 + cc) * HW + h0 + jx] = t[jx][cc];
    }
}

// ---- K7: cluster_new + reductions (n_tot, used, plogp) ----
__global__ void k_cluster(const float* __restrict__ cs, const float* __restrict__ counts,
                          float* __restrict__ o_cluster, float* __restrict__ scal) {
    int k = blockIdx.x * 256 + threadIdx.x;
    int lane = threadIdx.x & 63;
    float cnt = counts[k];
    float cn = DECAYF * cs[k] + ONE_M_DECAY * cnt;
    o_cluster[k] = cn;
    float used = cnt > 0.f ? 1.f : 0.f;
    float p = cnt * (1.0f / 16384.0f);
    float pl = p * logf(p + 1e-10f);
    cn   = wave_reduce_sum(cn);
    used = wave_reduce_sum(used);
    pl   = wave_reduce_sum(pl);
    if (lane == 0) {
        atomicAdd(&scal[1], cn);
        atomicAdd(&scal[2], used);
        atomicAdd(&scal[3], pl);
    }
}

// ---- K8: the 4 scalar outputs ----
__global__ void k_scalars(const float* __restrict__ scal, float* __restrict__ o_scal) {
    if (threadIdx.x == 0) {
        float sumsq = scal[0], used = scal[2], plogp = scal[3];
        o_scal[0] = BETAF * sumsq / (float)(N_TOK * DIM);  // loss
        o_scal[1] = sumsq / (float)N_TOK;                   // quant_error
        o_scal[2] = used * (1.0f / (float)KCB);             // utilization
        o_scal[3] = expf(-plogp);                           // perplexity
    }
}

// ---- K9: weight_new = embed_avg_new / smoothed ----
__global__ void k_weight_new(const float* __restrict__ o_embed, const float* __restrict__ o_cluster,
                             const float* __restrict__ scal, float* __restrict__ o_wnew) {
    int i4 = blockIdx.x * 256 + threadIdx.x;  // float4 index
    int k = i4 >> 6;
    float ntot = scal[1];
    float sm = (o_cluster[k] + EPSF) / (ntot + (float)KCB * EPSF) * ntot;
    float4 v = ((const float4*)o_embed)[i4];
    ((float4*)o_wnew)[i4] = make_float4(v.x / sm, v.y / sm, v.z / sm, v.w / sm);
}

extern "C" void kernel_launch(void* const* d_in, const int* in_sizes, int n_in,
                              void* d_out, int out_size, void* d_ws, size_t ws_size,
                              hipStream_t stream) {
    const float* z  = (const float*)d_in[0];
    const float* w  = (const float*)d_in[1];
    const float* cs = (const float*)d_in[2];
    const float* ea = (const float*)d_in[3];
    float* out = (float*)d_out;
    float* ws  = (float*)d_ws;

    float* zf     = ws;
    float* pmin   = ws + 4194304;
    int*   pidx   = (int*)(ws + 4259840);
    int*   token  = (int*)(ws + 4325376);
    float* counts = ws + 4341760;
    float* scal   = ws + 4358144;
    float* wnorm  = ws + 4358160;

    float* o_scal    = out + 4194304;   // loss, quant_error, utilization, perplexity
    float* o_wnew    = out + 4194308;
    float* o_cluster = out + 8388612;
    float* o_embed   = out + 8404996;

    hipMemsetAsync(counts, 0, (16384 + 16) * sizeof(float), stream);  // counts + scal
    k_init_embed<<<4096, 256, 0, stream>>>(ea, o_embed);
    k_transpose_z<<<dim3(32, 8, 16), 256, 0, stream>>>(z, zf);
    k_wnorm<<<4096, 256, 0, stream>>>(w, wnorm);
    k_dist<<<dim3(256, 4), 256, 0, stream>>>(zf, w, wnorm, pmin, pidx);
    k_token<<<64, 256, 0, stream>>>(pmin, pidx, token);
    k_gather<<<4096, 256, 0, stream>>>(token, zf, w, counts, o_embed, scal);
    k_write_out<<<dim3(32, 8, 16), 256, 0, stream>>>(token, w, out);
    k_cluster<<<64, 256, 0, stream>>>(cs, counts, o_cluster, scal);
    k_scalars<<<1, 64, 0, stream>>>(scal, o_scal);
    k_weight_new<<<4096, 256, 0, stream>>>(o_embed, o_cluster, scal, o_wnew);
}

// Round 2
// 868.951 us; speedup vs baseline: 5.1277x; 5.1277x over previous
//
#include <hip/hip_runtime.h>

#define N_TOK 16384
#define KCB   16384
#define DIM   256
#define HW    1024
#define DECAYF 0.8f
#define ONE_M_DECAY 0.2f
#define BETAF 0.25f
#define EPSF  1e-5f

typedef __attribute__((ext_vector_type(8))) short bf16x8;
typedef __attribute__((ext_vector_type(4))) float f32x4;

__device__ __forceinline__ float wave_reduce_sum(float s) {
    #pragma unroll
    for (int o = 32; o > 0; o >>= 1) s += __shfl_down(s, o);
    return s;
}

__device__ __forceinline__ unsigned short f2bf(float x) {
    union { float f; unsigned int u; } a; a.f = x;
    unsigned int r = a.u + 0x7fffu + ((a.u >> 16) & 1u);
    return (unsigned short)(r >> 16);
}
__device__ __forceinline__ float bf2f(unsigned short h) {
    union { unsigned int u; float f; } a; a.u = ((unsigned int)h) << 16;
    return a.f;
}

// ---- K1: transpose z[b][c][hw] -> zf[b*HW+hw][c] ----
__global__ void k_transpose_z(const float* __restrict__ z, float* __restrict__ zf) {
    __shared__ float t[32][33];
    int b  = blockIdx.z;
    int c0 = blockIdx.y * 32;
    int h0 = blockIdx.x * 32;
    int tid = threadIdx.x;
    int jx = tid & 31, iy = tid >> 5;
    const float* zb = z + (size_t)b * DIM * HW;
    #pragma unroll
    for (int p = 0; p < 4; ++p) {
        int ci = iy + p * 8;
        t[ci][jx] = zb[(size_t)(c0 + ci) * HW + h0 + jx];
    }
    __syncthreads();
    float* zfb = zf + (size_t)b * HW * DIM;
    #pragma unroll
    for (int p = 0; p < 4; ++p) {
        int hh = iy + p * 8;
        zfb[(size_t)(h0 + hh) * DIM + c0 + jx] = t[jx][hh];
    }
}

// ---- K2: split fp32 row-major [R][256] into bf16 hi/lo ----
__global__ void k_split(const float* __restrict__ src, unsigned short* __restrict__ hi,
                        unsigned short* __restrict__ lo) {
    int i4 = blockIdx.x * 256 + threadIdx.x;      // float4 index
    float4 v = ((const float4*)src)[i4];
    ushort4 h, l;
    h.x = f2bf(v.x); l.x = f2bf(v.x - bf2f(h.x));
    h.y = f2bf(v.y); l.y = f2bf(v.y - bf2f(h.y));
    h.z = f2bf(v.z); l.z = f2bf(v.z - bf2f(h.z));
    h.w = f2bf(v.w); l.w = f2bf(v.w - bf2f(h.w));
    ((ushort4*)hi)[i4] = h;
    ((ushort4*)lo)[i4] = l;
}

// ---- K3: wnorm[k] = |w_k|^2 ----
__global__ void k_wnorm(const float* __restrict__ w, float* __restrict__ wnorm) {
    int wv = blockIdx.x * 4 + (threadIdx.x >> 6);
    int lane = threadIdx.x & 63;
    float4 v = ((const float4*)(w + (size_t)wv * DIM))[lane];
    float s = v.x * v.x + v.y * v.y + v.z * v.z + v.w * v.w;
    s = wave_reduce_sum(s);
    if (lane == 0) wnorm[wv] = s;
}

// ---- K4: MFMA GEMM (3-term split bf16) + fused argmin ----
// C[n][k] = z.w over K'=768 (segments: Ah*Bh, Ah*Bl, Al*Bh). 128x128 tile.
__global__ __launch_bounds__(256) void k_gemm_argmin(
    const unsigned short* __restrict__ Ah, const unsigned short* __restrict__ Al,
    const unsigned short* __restrict__ Bh, const unsigned short* __restrict__ Bl,
    const float* __restrict__ wnorm, unsigned long long* __restrict__ pout) {
    __shared__ unsigned short As[128 * 32];
    __shared__ unsigned short Bs[128 * 32];
    __shared__ unsigned long long red[2][128];

    int tid  = threadIdx.x;
    int wave = tid >> 6, lane = tid & 63;
    int g16  = lane >> 4, r16 = lane & 15;
    int n0   = blockIdx.x * 128;   // token rows
    int kb   = blockIdx.y;         // code block
    int c0   = kb * 128;

    f32x4 acc[4][4];
    #pragma unroll
    for (int mt = 0; mt < 4; ++mt)
        #pragma unroll
        for (int nt = 0; nt < 4; ++nt)
            acc[mt][nt] = (f32x4){0.f, 0.f, 0.f, 0.f};

    // staging chunk ids (16B chunks; slot s -> row m=s>>2, stored pk = (s&3)^(m&3))
    int sA0 = (wave * 2 + 0) * 64 + lane;
    int sA1 = (wave * 2 + 1) * 64 + lane;

    for (int ks = 0; ks < 24; ++ks) {
        int seg  = ks >> 3;          // 0,1,2
        int koff = (ks & 7) * 32;    // k offset within 256-wide segment
        const unsigned short* Aseg = (seg == 2) ? Al : Ah;
        const unsigned short* Bseg = (seg == 1) ? Bl : Bh;
        __syncthreads();
        #pragma unroll
        for (int j = 0; j < 2; ++j) {
            int s = j ? sA1 : sA0;
            int m = s >> 2;
            int pk = (s & 3) ^ (m & 3);
            const unsigned int* ga = (const unsigned int*)(Aseg + (size_t)(n0 + m) * 256 + koff + pk * 8);
            const unsigned int* gb = (const unsigned int*)(Bseg + (size_t)(c0 + m) * 256 + koff + pk * 8);
            unsigned int* la = (unsigned int*)&As[(size_t)((wave * 2 + j) * 64) * 8];
            unsigned int* lb = (unsigned int*)&Bs[(size_t)((wave * 2 + j) * 64) * 8];
            __builtin_amdgcn_global_load_lds((const __attribute__((address_space(1))) unsigned int*)ga,
                                             (__attribute__((address_space(3))) unsigned int*)la, 16, 0, 0);
            __builtin_amdgcn_global_load_lds((const __attribute__((address_space(1))) unsigned int*)gb,
                                             (__attribute__((address_space(3))) unsigned int*)lb, 16, 0, 0);
        }
        __syncthreads();
        bf16x8 af[4], bfr[4];
        #pragma unroll
        for (int mt = 0; mt < 4; ++mt) {
            int row = (wave >> 1) * 64 + mt * 16 + r16;
            int slot = row * 4 + (g16 ^ (row & 3));
            af[mt] = *(const bf16x8*)&As[slot * 8];
        }
        #pragma unroll
        for (int nt = 0; nt < 4; ++nt) {
            int row = (wave & 1) * 64 + nt * 16 + r16;
            int slot = row * 4 + (g16 ^ (row & 3));
            bfr[nt] = *(const bf16x8*)&Bs[slot * 8];
        }
        #pragma unroll
        for (int mt = 0; mt < 4; ++mt)
            #pragma unroll
            for (int nt = 0; nt < 4; ++nt)
                acc[mt][nt] = __builtin_amdgcn_mfma_f32_16x16x32_bf16(af[mt], bfr[nt], acc[mt][nt], 0, 0, 0);
    }

    // epilogue: score = |w|^2 - 2 z.w ; packed (score,idx) argmin
    float wn[4];
    int   code[4];
    #pragma unroll
    for (int nt = 0; nt < 4; ++nt) {
        code[nt] = c0 + (wave & 1) * 64 + nt * 16 + r16;
        wn[nt] = wnorm[code[nt]];
    }
    unsigned long long best[4][4];
    #pragma unroll
    for (int mt = 0; mt < 4; ++mt)
        #pragma unroll
        for (int rg = 0; rg < 4; ++rg) {
            unsigned long long b = ~0ull;
            #pragma unroll
            for (int nt = 0; nt < 4; ++nt) {
                float s = wn[nt] - 2.0f * acc[mt][nt][rg];
                unsigned int u = __float_as_uint(s);
                u = (u & 0x80000000u) ? ~u : (u | 0x80000000u);
                unsigned long long p = ((unsigned long long)u << 32) | (unsigned int)code[nt];
                b = p < b ? p : b;
            }
            best[mt][rg] = b;
        }
    // reduce across the 16 lanes of each row-group (xor 1,2,4,8 keeps l>>4 fixed)
    #pragma unroll
    for (int mt = 0; mt < 4; ++mt)
        #pragma unroll
        for (int rg = 0; rg < 4; ++rg) {
            unsigned long long b = best[mt][rg];
            #pragma unroll
            for (int off = 1; off < 16; off <<= 1) {
                unsigned int blo = (unsigned int)b, bhi = (unsigned int)(b >> 32);
                blo = __shfl_xor(blo, off);
                bhi = __shfl_xor(bhi, off);
                unsigned long long o = ((unsigned long long)bhi << 32) | blo;
                b = o < b ? o : b;
            }
            best[mt][rg] = b;
        }
    if (r16 == 0) {
        #pragma unroll
        for (int mt = 0; mt < 4; ++mt)
            #pragma unroll
            for (int rg = 0; rg < 4; ++rg)
                red[wave & 1][(wave >> 1) * 64 + mt * 16 + g16 * 4 + rg] = best[mt][rg];
    }
    __syncthreads();
    if (tid < 128) {
        unsigned long long a = red[0][tid], b = red[1][tid];
        pout[(size_t)kb * N_TOK + n0 + tid] = a < b ? a : b;
    }
}

// ---- K5: reduce 128 kblock partials -> token[n] ----
__global__ void k_token(const unsigned long long* __restrict__ pout, int* __restrict__ token) {
    int n = blockIdx.x * 256 + threadIdx.x;
    unsigned long long b = ~0ull;
    for (int kbl = 0; kbl < 128; ++kbl) {
        unsigned long long v = pout[(size_t)kbl * N_TOK + n];
        b = v < b ? v : b;
    }
    token[n] = (int)(b & 0xffffffffu);
}

// ---- K_init: embed_avg_new = DECAY * embed_avg ----
__global__ void k_init_embed(const float* __restrict__ ea, float* __restrict__ o_embed) {
    int i = blockIdx.x * 256 + threadIdx.x;
    float4 v = ((const float4*)ea)[i];
    ((float4*)o_embed)[i] = make_float4(DECAYF * v.x, DECAYF * v.y, DECAYF * v.z, DECAYF * v.w);
}

// ---- K6: gather + scatter (sumsq, counts, embed_sum) ----
__global__ void k_gather(const int* __restrict__ token, const float* __restrict__ zf,
                         const float* __restrict__ w, float* __restrict__ counts,
                         float* __restrict__ o_embed, float* __restrict__ scal) {
    int n = blockIdx.x * 4 + (threadIdx.x >> 6);
    int lane = threadIdx.x & 63;
    int t = token[n];
    float4 wv = ((const float4*)(w  + (size_t)t * DIM))[lane];
    float4 zv = ((const float4*)(zf + (size_t)n * DIM))[lane];
    float dx = wv.x - zv.x, dy = wv.y - zv.y, dz = wv.z - zv.z, dw = wv.w - zv.w;
    float s = dx * dx + dy * dy + dz * dz + dw * dw;
    s = wave_reduce_sum(s);
    if (lane == 0) {
        atomicAdd(&scal[0], s);
        atomicAdd(&counts[t], 1.0f);
    }
    float* ed = o_embed + (size_t)t * DIM + lane * 4;
    atomicAdd(ed + 0, ONE_M_DECAY * zv.x);
    atomicAdd(ed + 1, ONE_M_DECAY * zv.y);
    atomicAdd(ed + 2, ONE_M_DECAY * zv.z);
    atomicAdd(ed + 3, ONE_M_DECAY * zv.w);
}

// ---- K7: out[b][c][hw] = weight[token[b*HW+hw]][c] ----
__global__ void k_write_out(const int* __restrict__ token, const float* __restrict__ w,
                            float* __restrict__ out) {
    __shared__ float t[32][33];
    __shared__ int tok[32];
    int b = blockIdx.z, c0 = blockIdx.y * 32, h0 = blockIdx.x * 32;
    int tid = threadIdx.x, jx = tid & 31, iy = tid >> 5;
    if (tid < 32) tok[tid] = token[b * HW + h0 + tid];
    __syncthreads();
    #pragma unroll
    for (int p = 0; p < 4; ++p) {
        int hh = iy + p * 8;
        t[hh][jx] = w[(size_t)tok[hh] * DIM + c0 + jx];
    }
    __syncthreads();
    #pragma unroll
    for (int p = 0; p < 4; ++p) {
        int cc = iy + p * 8;
        out[(size_t)b * DIM * HW + (size_t)(c0 + cc) * HW + h0 + jx] = t[jx][cc];
    }
}

// ---- K8: cluster_new + reductions ----
__global__ void k_cluster(const float* __restrict__ cs, const float* __restrict__ counts,
                          float* __restrict__ o_cluster, float* __restrict__ scal) {
    int k = blockIdx.x * 256 + threadIdx.x;
    int lane = threadIdx.x & 63;
    float cnt = counts[k];
    float cn = DECAYF * cs[k] + ONE_M_DECAY * cnt;
    o_cluster[k] = cn;
    float used = cnt > 0.f ? 1.f : 0.f;
    float p = cnt * (1.0f / 16384.0f);
    float pl = p * logf(p + 1e-10f);
    cn   = wave_reduce_sum(cn);
    used = wave_reduce_sum(used);
    pl   = wave_reduce_sum(pl);
    if (lane == 0) {
        atomicAdd(&scal[1], cn);
        atomicAdd(&scal[2], used);
        atomicAdd(&scal[3], pl);
    }
}

// ---- K9: scalar outputs ----
__global__ void k_scalars(const float* __restrict__ scal, float* __restrict__ o_scal) {
    if (threadIdx.x == 0) {
        float sumsq = scal[0], used = scal[2], plogp = scal[3];
        o_scal[0] = BETAF * sumsq / (float)(N_TOK * DIM);
        o_scal[1] = sumsq / (float)N_TOK;
        o_scal[2] = used * (1.0f / (float)KCB);
        o_scal[3] = expf(-plogp);
    }
}

// ---- K10: weight_new ----
__global__ void k_weight_new(const float* __restrict__ o_embed, const float* __restrict__ o_cluster,
                             const float* __restrict__ scal, float* __restrict__ o_wnew) {
    int i4 = blockIdx.x * 256 + threadIdx.x;
    int k = i4 >> 6;
    float ntot = scal[1];
    float sm = (o_cluster[k] + EPSF) / (ntot + (float)KCB * EPSF) * ntot;
    float4 v = ((const float4*)o_embed)[i4];
    ((float4*)o_wnew)[i4] = make_float4(v.x / sm, v.y / sm, v.z / sm, v.w / sm);
}

extern "C" void kernel_launch(void* const* d_in, const int* in_sizes, int n_in,
                              void* d_out, int out_size, void* d_ws, size_t ws_size,
                              hipStream_t stream) {
    const float* z  = (const float*)d_in[0];
    const float* w  = (const float*)d_in[1];
    const float* cs = (const float*)d_in[2];
    const float* ea = (const float*)d_in[3];
    float* out = (float*)d_out;

    char* w8 = (char*)d_ws;
    unsigned short* Ah = (unsigned short*)(w8 + 0);
    unsigned short* Al = (unsigned short*)(w8 + 8388608);
    unsigned short* Bh = (unsigned short*)(w8 + 16777216);
    unsigned short* Bl = (unsigned short*)(w8 + 25165824);
    float* wnorm  = (float*)(w8 + 33554432);
    int*   token  = (int*)(w8 + 33619968);
    float* counts = (float*)(w8 + 33685504);
    float* scal   = (float*)(w8 + 33751040);

    // temporaries aliased into d_out (finalized later in the launch):
    float* zf = out;                                            // overwritten by k_write_out
    unsigned long long* pout = (unsigned long long*)(out + 4194308); // overwritten by k_weight_new
    float* o_scal    = out + 4194304;
    float* o_wnew    = out + 4194308;
    float* o_cluster = out + 8388612;
    float* o_embed   = out + 8404996;

    hipMemsetAsync(counts, 0, 65536 + 64, stream);  // counts + scal
    k_transpose_z<<<dim3(32, 8, 16), 256, 0, stream>>>(z, zf);
    k_split<<<4096, 256, 0, stream>>>(zf, Ah, Al);
    k_split<<<4096, 256, 0, stream>>>(w, Bh, Bl);
    k_wnorm<<<4096, 256, 0, stream>>>(w, wnorm);
    k_init_embed<<<4096, 256, 0, stream>>>(ea, o_embed);
    k_gemm_argmin<<<dim3(128, 128), 256, 0, stream>>>(Ah, Al, Bh, Bl, wnorm, pout);
    k_token<<<64, 256, 0, stream>>>(pout, token);
    k_gather<<<4096, 256, 0, stream>>>(token, zf, w, counts, o_embed, scal);
    k_write_out<<<dim3(32, 8, 16), 256, 0, stream>>>(token, w, out);
    k_cluster<<<64, 256, 0, stream>>>(cs, counts, o_cluster, scal);
    k_scalars<<<1, 64, 0, stream>>>(scal, o_scal);
    k_weight_new<<<4096, 256, 0, stream>>>(o_embed, o_cluster, scal, o_wnew);
}

// Round 3
// 724.225 us; speedup vs baseline: 6.1524x; 1.1998x over previous
//
#include <hip/hip_runtime.h>

#define N_TOK 16384
#define KCB   16384
#define DIM   256
#define HW    1024
#define DECAYF 0.8f
#define ONE_M_DECAY 0.2f
#define BETAF 0.25f
#define EPSF  1e-5f

typedef __attribute__((ext_vector_type(8))) short bf16x8;
typedef __attribute__((ext_vector_type(4))) float f32x4;

__device__ __forceinline__ float wave_reduce_sum(float s) {
    #pragma unroll
    for (int o = 32; o > 0; o >>= 1) s += __shfl_down(s, o);
    return s;
}

__device__ __forceinline__ unsigned short f2bf(float x) {
    union { float f; unsigned int u; } a; a.f = x;
    unsigned int r = a.u + 0x7fffu + ((a.u >> 16) & 1u);
    return (unsigned short)(r >> 16);
}

// ---- K1: transpose z[b][c][hw] -> zf[n][d] (fp32) + Ah[n][d] (bf16) ----
__global__ void k_transpose_z(const float* __restrict__ z, float* __restrict__ zf,
                              unsigned short* __restrict__ Ah) {
    __shared__ float t[32][33];
    int b  = blockIdx.z;
    int c0 = blockIdx.y * 32;
    int h0 = blockIdx.x * 32;
    int tid = threadIdx.x;
    int jx = tid & 31, iy = tid >> 5;
    const float* zb = z + (size_t)b * DIM * HW;
    #pragma unroll
    for (int p = 0; p < 4; ++p) {
        int ci = iy + p * 8;
        t[ci][jx] = zb[(size_t)(c0 + ci) * HW + h0 + jx];
    }
    __syncthreads();
    #pragma unroll
    for (int p = 0; p < 4; ++p) {
        int hh = iy + p * 8;
        size_t idx = (size_t)(b * HW + h0 + hh) * DIM + c0 + jx;
        float v = t[jx][hh];
        zf[idx] = v;
        Ah[idx] = f2bf(v);
    }
}

// ---- K2: Bh[k][d] = bf16(w), wnorm[k] = |w_k|^2 (fused) ----
__global__ void k_prep_w(const float* __restrict__ w, unsigned short* __restrict__ Bh,
                         float* __restrict__ wnorm) {
    int wv = blockIdx.x * 4 + (threadIdx.x >> 6);
    int lane = threadIdx.x & 63;
    float4 v = ((const float4*)(w + (size_t)wv * DIM))[lane];
    ushort4 h;
    h.x = f2bf(v.x); h.y = f2bf(v.y); h.z = f2bf(v.z); h.w = f2bf(v.w);
    ((ushort4*)(Bh + (size_t)wv * DIM))[lane] = h;
    float s = v.x * v.x + v.y * v.y + v.z * v.z + v.w * v.w;
    s = wave_reduce_sum(s);
    if (lane == 0) wnorm[wv] = s;
}

// ---- K3: hi-only bf16 MFMA GEMM + fused TOP-2 argmin per (token, kblock) ----
__global__ __launch_bounds__(256) void k_gemm_argmin(
    const unsigned short* __restrict__ Ah, const unsigned short* __restrict__ Bh,
    const float* __restrict__ wnorm, ulonglong2* __restrict__ pout2) {
    __shared__ unsigned short As[128 * 32];
    __shared__ unsigned short Bs[128 * 32];
    __shared__ unsigned long long red1[2][128];
    __shared__ unsigned long long red2[2][128];

    int tid  = threadIdx.x;
    int wave = tid >> 6, lane = tid & 63;
    int g16  = lane >> 4, r16 = lane & 15;
    int n0   = blockIdx.x * 128;
    int kb   = blockIdx.y;
    int c0   = kb * 128;

    f32x4 acc[4][4];
    #pragma unroll
    for (int mt = 0; mt < 4; ++mt)
        #pragma unroll
        for (int nt = 0; nt < 4; ++nt)
            acc[mt][nt] = (f32x4){0.f, 0.f, 0.f, 0.f};

    int sA0 = (wave * 2 + 0) * 64 + lane;
    int sA1 = (wave * 2 + 1) * 64 + lane;

    for (int ks = 0; ks < 8; ++ks) {
        int koff = ks * 32;
        __syncthreads();
        #pragma unroll
        for (int j = 0; j < 2; ++j) {
            int s = j ? sA1 : sA0;
            int m = s >> 2;
            int pk = (s & 3) ^ (m & 3);
            const unsigned int* ga = (const unsigned int*)(Ah + (size_t)(n0 + m) * 256 + koff + pk * 8);
            const unsigned int* gb = (const unsigned int*)(Bh + (size_t)(c0 + m) * 256 + koff + pk * 8);
            unsigned int* la = (unsigned int*)&As[(size_t)((wave * 2 + j) * 64) * 8];
            unsigned int* lb = (unsigned int*)&Bs[(size_t)((wave * 2 + j) * 64) * 8];
            __builtin_amdgcn_global_load_lds((const __attribute__((address_space(1))) unsigned int*)ga,
                                             (__attribute__((address_space(3))) unsigned int*)la, 16, 0, 0);
            __builtin_amdgcn_global_load_lds((const __attribute__((address_space(1))) unsigned int*)gb,
                                             (__attribute__((address_space(3))) unsigned int*)lb, 16, 0, 0);
        }
        __syncthreads();
        bf16x8 af[4], bfr[4];
        #pragma unroll
        for (int mt = 0; mt < 4; ++mt) {
            int row = (wave >> 1) * 64 + mt * 16 + r16;
            int slot = row * 4 + (g16 ^ (row & 3));
            af[mt] = *(const bf16x8*)&As[slot * 8];
        }
        #pragma unroll
        for (int nt = 0; nt < 4; ++nt) {
            int row = (wave & 1) * 64 + nt * 16 + r16;
            int slot = row * 4 + (g16 ^ (row & 3));
            bfr[nt] = *(const bf16x8*)&Bs[slot * 8];
        }
        #pragma unroll
        for (int mt = 0; mt < 4; ++mt)
            #pragma unroll
            for (int nt = 0; nt < 4; ++nt)
                acc[mt][nt] = __builtin_amdgcn_mfma_f32_16x16x32_bf16(af[mt], bfr[nt], acc[mt][nt], 0, 0, 0);
    }

    // epilogue: score = |w|^2 - 2 z.w ; keep top-2 (packed score,idx)
    float wn[4];
    int   code[4];
    #pragma unroll
    for (int nt = 0; nt < 4; ++nt) {
        code[nt] = c0 + (wave & 1) * 64 + nt * 16 + r16;
        wn[nt] = wnorm[code[nt]];
    }
    #pragma unroll
    for (int mt = 0; mt < 4; ++mt) {
        #pragma unroll
        for (int rg = 0; rg < 4; ++rg) {
            unsigned long long b1 = ~0ull, b2 = ~0ull;
            #pragma unroll
            for (int nt = 0; nt < 4; ++nt) {
                float s = wn[nt] - 2.0f * acc[mt][nt][rg];
                unsigned int u = __float_as_uint(s);
                u = (u & 0x80000000u) ? ~u : (u | 0x80000000u);
                unsigned long long p = ((unsigned long long)u << 32) | (unsigned int)code[nt];
                if (p < b1) { b2 = b1; b1 = p; }
                else if (p < b2) { b2 = p; }
            }
            #pragma unroll
            for (int off = 1; off < 16; off <<= 1) {
                unsigned long long o1 = __shfl_xor(b1, off);
                unsigned long long o2 = __shfl_xor(b2, off);
                unsigned long long m1 = b1 < o1 ? b1 : o1;
                unsigned long long hi = b1 < o1 ? o1 : b1;
                unsigned long long lo = b2 < o2 ? b2 : o2;
                b1 = m1;
                b2 = hi < lo ? hi : lo;
            }
            if (r16 == 0) {
                int row = (wave >> 1) * 64 + mt * 16 + g16 * 4 + rg;
                red1[wave & 1][row] = b1;
                red2[wave & 1][row] = b2;
            }
        }
    }
    __syncthreads();
    if (tid < 128) {
        unsigned long long a1 = red1[0][tid], a2 = red2[0][tid];
        unsigned long long c1 = red1[1][tid], c2 = red2[1][tid];
        unsigned long long m1 = a1 < c1 ? a1 : c1;
        unsigned long long hi = a1 < c1 ? c1 : a1;
        unsigned long long lo = a2 < c2 ? a2 : c2;
        pout2[(size_t)kb * N_TOK + n0 + tid] = make_ulonglong2(m1, hi < lo ? hi : lo);
    }
}

// ---- K4: merge 128 kblock top-2 partials -> candidate pair per token ----
__global__ void k_token(const ulonglong2* __restrict__ pout2, int2* __restrict__ cand) {
    int n = blockIdx.x * 256 + threadIdx.x;
    unsigned long long b1 = ~0ull, b2 = ~0ull;
    for (int kbl = 0; kbl < 128; ++kbl) {
        ulonglong2 p = pout2[(size_t)kbl * N_TOK + n];
        unsigned long long m1 = b1 < p.x ? b1 : p.x;
        unsigned long long hi = b1 < p.x ? p.x : b1;
        unsigned long long lo = b2 < p.y ? b2 : p.y;
        b1 = m1;
        b2 = hi < lo ? hi : lo;
    }
    cand[n] = make_int2((int)(b1 & 0xffffffffu), (int)(b2 & 0xffffffffu));
}

// ---- K5: exact fp32 rescore of the 2 candidates -> token[n] ----
__global__ void k_rescore(const int2* __restrict__ cand, const float* __restrict__ zf,
                          const float* __restrict__ w, int* __restrict__ token) {
    int n = blockIdx.x * 4 + (threadIdx.x >> 6);
    int lane = threadIdx.x & 63;
    int2 c = cand[n];
    float4 zv = ((const float4*)(zf + (size_t)n * DIM))[lane];
    float4 w1 = ((const float4*)(w + (size_t)c.x * DIM))[lane];
    float4 w2 = ((const float4*)(w + (size_t)c.y * DIM))[lane];
    float ax = zv.x - w1.x, ay = zv.y - w1.y, az = zv.z - w1.z, aw = zv.w - w1.w;
    float bx = zv.x - w2.x, by = zv.y - w2.y, bz = zv.z - w2.z, bw = zv.w - w2.w;
    float d1 = ax * ax + ay * ay + az * az + aw * aw;
    float d2 = bx * bx + by * by + bz * bz + bw * bw;
    d1 = wave_reduce_sum(d1);
    d2 = wave_reduce_sum(d2);
    if (lane == 0)
        token[n] = (d2 < d1 || (d2 == d1 && c.y < c.x)) ? c.y : c.x;
}

// ---- K_init: embed_avg_new = DECAY * embed_avg ----
__global__ void k_init_embed(const float* __restrict__ ea, float* __restrict__ o_embed) {
    int i = blockIdx.x * 256 + threadIdx.x;
    float4 v = ((const float4*)ea)[i];
    ((float4*)o_embed)[i] = make_float4(DECAYF * v.x, DECAYF * v.y, DECAYF * v.z, DECAYF * v.w);
}

// ---- K6: gather + scatter (sumsq, counts, embed_sum) ----
__global__ void k_gather(const int* __restrict__ token, const float* __restrict__ zf,
                         const float* __restrict__ w, float* __restrict__ counts,
                         float* __restrict__ o_embed, float* __restrict__ scal) {
    int n = blockIdx.x * 4 + (threadIdx.x >> 6);
    int lane = threadIdx.x & 63;
    int t = token[n];
    float4 wv = ((const float4*)(w  + (size_t)t * DIM))[lane];
    float4 zv = ((const float4*)(zf + (size_t)n * DIM))[lane];
    float dx = wv.x - zv.x, dy = wv.y - zv.y, dz = wv.z - zv.z, dw = wv.w - zv.w;
    float s = dx * dx + dy * dy + dz * dz + dw * dw;
    s = wave_reduce_sum(s);
    if (lane == 0) {
        atomicAdd(&scal[0], s);
        atomicAdd(&counts[t], 1.0f);
    }
    float* ed = o_embed + (size_t)t * DIM + lane * 4;
    atomicAdd(ed + 0, ONE_M_DECAY * zv.x);
    atomicAdd(ed + 1, ONE_M_DECAY * zv.y);
    atomicAdd(ed + 2, ONE_M_DECAY * zv.z);
    atomicAdd(ed + 3, ONE_M_DECAY * zv.w);
}

// ---- K7: out[b][c][hw] = weight[token[b*HW+hw]][c] ----
__global__ void k_write_out(const int* __restrict__ token, const float* __restrict__ w,
                            float* __restrict__ out) {
    __shared__ float t[32][33];
    __shared__ int tok[32];
    int b = blockIdx.z, c0 = blockIdx.y * 32, h0 = blockIdx.x * 32;
    int tid = threadIdx.x, jx = tid & 31, iy = tid >> 5;
    if (tid < 32) tok[tid] = token[b * HW + h0 + tid];
    __syncthreads();
    #pragma unroll
    for (int p = 0; p < 4; ++p) {
        int hh = iy + p * 8;
        t[hh][jx] = w[(size_t)tok[hh] * DIM + c0 + jx];
    }
    __syncthreads();
    #pragma unroll
    for (int p = 0; p < 4; ++p) {
        int cc = iy + p * 8;
        out[(size_t)b * DIM * HW + (size_t)(c0 + cc) * HW + h0 + jx] = t[jx][cc];
    }
}

// ---- K8: cluster_new + reductions ----
__global__ void k_cluster(const float* __restrict__ cs, const float* __restrict__ counts,
                          float* __restrict__ o_cluster, float* __restrict__ scal) {
    int k = blockIdx.x * 256 + threadIdx.x;
    int lane = threadIdx.x & 63;
    float cnt = counts[k];
    float cn = DECAYF * cs[k] + ONE_M_DECAY * cnt;
    o_cluster[k] = cn;
    float used = cnt > 0.f ? 1.f : 0.f;
    float p = cnt * (1.0f / 16384.0f);
    float pl = p * logf(p + 1e-10f);
    cn   = wave_reduce_sum(cn);
    used = wave_reduce_sum(used);
    pl   = wave_reduce_sum(pl);
    if (lane == 0) {
        atomicAdd(&scal[1], cn);
        atomicAdd(&scal[2], used);
        atomicAdd(&scal[3], pl);
    }
}

// ---- K9: scalar outputs ----
__global__ void k_scalars(const float* __restrict__ scal, float* __restrict__ o_scal) {
    if (threadIdx.x == 0) {
        float sumsq = scal[0], used = scal[2], plogp = scal[3];
        o_scal[0] = BETAF * sumsq / (float)(N_TOK * DIM);
        o_scal[1] = sumsq / (float)N_TOK;
        o_scal[2] = used * (1.0f / (float)KCB);
        o_scal[3] = expf(-plogp);
    }
}

// ---- K10: weight_new ----
__global__ void k_weight_new(const float* __restrict__ o_embed, const float* __restrict__ o_cluster,
                             const float* __restrict__ scal, float* __restrict__ o_wnew) {
    int i4 = blockIdx.x * 256 + threadIdx.x;
    int k = i4 >> 6;
    float ntot = scal[1];
    float sm = (o_cluster[k] + EPSF) / (ntot + (float)KCB * EPSF) * ntot;
    float4 v = ((const float4*)o_embed)[i4];
    ((float4*)o_wnew)[i4] = make_float4(v.x / sm, v.y / sm, v.z / sm, v.w / sm);
}

extern "C" void kernel_launch(void* const* d_in, const int* in_sizes, int n_in,
                              void* d_out, int out_size, void* d_ws, size_t ws_size,
                              hipStream_t stream) {
    const float* z  = (const float*)d_in[0];
    const float* w  = (const float*)d_in[1];
    const float* cs = (const float*)d_in[2];
    const float* ea = (const float*)d_in[3];
    float* out = (float*)d_out;

    char* w8 = (char*)d_ws;
    unsigned short* Ah = (unsigned short*)(w8 + 0);
    unsigned short* Bh = (unsigned short*)(w8 + 8388608);
    float* wnorm  = (float*)(w8 + 16777216);
    int*   token  = (int*)(w8 + 16842752);
    int2*  cand   = (int2*)(w8 + 16908288);
    float* counts = (float*)(w8 + 17039360);
    float* scal   = (float*)(w8 + 17104896);

    // aliased into d_out (regions finalized later in the launch):
    float* zf = out;                                   // overwritten by k_write_out
    ulonglong2* pout2 = (ulonglong2*)(out + 4194308);  // overlaps o_wnew/o_cluster/o_embed,
                                                       // all written after k_token
    float* o_scal    = out + 4194304;
    float* o_wnew    = out + 4194308;
    float* o_cluster = out + 8388612;
    float* o_embed   = out + 8404996;

    hipMemsetAsync(counts, 0, 65536 + 64, stream);  // counts + scal
    k_transpose_z<<<dim3(32, 8, 16), 256, 0, stream>>>(z, zf, Ah);
    k_prep_w<<<4096, 256, 0, stream>>>(w, Bh, wnorm);
    k_gemm_argmin<<<dim3(128, 128), 256, 0, stream>>>(Ah, Bh, wnorm, pout2);
    k_token<<<64, 256, 0, stream>>>(pout2, cand);
    k_rescore<<<4096, 256, 0, stream>>>(cand, zf, w, token);
    k_init_embed<<<4096, 256, 0, stream>>>(ea, o_embed);
    k_gather<<<4096, 256, 0, stream>>>(token, zf, w, counts, o_embed, scal);
    k_write_out<<<dim3(32, 8, 16), 256, 0, stream>>>(token, w, out);
    k_cluster<<<64, 256, 0, stream>>>(cs, counts, o_cluster, scal);
    k_scalars<<<1, 64, 0, stream>>>(scal, o_scal);
    k_weight_new<<<4096, 256, 0, stream>>>(o_embed, o_cluster, scal, o_wnew);
}

// Round 4
// 532.732 us; speedup vs baseline: 8.3640x; 1.3595x over previous
//
#include <hip/hip_runtime.h>

#define N_TOK 16384
#define KCB   16384
#define DIM   256
#define HW    1024
#define DECAYF 0.8f
#define ONE_M_DECAY 0.2f
#define BETAF 0.25f
#define EPSF  1e-5f
#define STRIPS 8
#define KB_PER 16

typedef __attribute__((ext_vector_type(8))) short bf16x8;
typedef __attribute__((ext_vector_type(4))) float f32x4;

__device__ __forceinline__ float wave_reduce_sum(float s) {
    #pragma unroll
    for (int o = 32; o > 0; o >>= 1) s += __shfl_down(s, o);
    return s;
}

__device__ __forceinline__ unsigned short f2bf(float x) {
    union { float f; unsigned int u; } a; a.f = x;
    unsigned int r = a.u + 0x7fffu + ((a.u >> 16) & 1u);
    return (unsigned short)(r >> 16);
}

// ---- K1: transpose z[b][c][hw] -> zf[n][d] (fp32) + Ah[n][d] (bf16) ----
__global__ void k_transpose_z(const float* __restrict__ z, float* __restrict__ zf,
                              unsigned short* __restrict__ Ah) {
    __shared__ float t[32][33];
    int b  = blockIdx.z;
    int c0 = blockIdx.y * 32;
    int h0 = blockIdx.x * 32;
    int tid = threadIdx.x;
    int jx = tid & 31, iy = tid >> 5;
    const float* zb = z + (size_t)b * DIM * HW;
    #pragma unroll
    for (int p = 0; p < 4; ++p) {
        int ci = iy + p * 8;
        t[ci][jx] = zb[(size_t)(c0 + ci) * HW + h0 + jx];
    }
    __syncthreads();
    #pragma unroll
    for (int p = 0; p < 4; ++p) {
        int hh = iy + p * 8;
        size_t idx = (size_t)(b * HW + h0 + hh) * DIM + c0 + jx;
        float v = t[jx][hh];
        zf[idx] = v;
        Ah[idx] = f2bf(v);
    }
}

// ---- K2: Bh[k][d] = bf16(w), wnorm[k] = |w_k|^2 ----
__global__ void k_prep_w(const float* __restrict__ w, unsigned short* __restrict__ Bh,
                         float* __restrict__ wnorm) {
    int wv = blockIdx.x * 4 + (threadIdx.x >> 6);
    int lane = threadIdx.x & 63;
    float4 v = ((const float4*)(w + (size_t)wv * DIM))[lane];
    ushort4 h;
    h.x = f2bf(v.x); h.y = f2bf(v.y); h.z = f2bf(v.z); h.w = f2bf(v.w);
    ((ushort4*)(Bh + (size_t)wv * DIM))[lane] = h;
    float s = v.x * v.x + v.y * v.y + v.z * v.z + v.w * v.w;
    s = wave_reduce_sum(s);
    if (lane == 0) wnorm[wv] = s;
}

// ---- K3: bf16 MFMA GEMM, A-resident, in-kernel kb sweep, packed-u32 top-2 ----
// grid (128 n-tiles, 8 strips); strip covers 16 kblocks of 128 codes.
// packed = bits(score+0.0625) & ~0x7FF | (kbi<<7 | half<<6 | nt<<4 | r16)
__global__ __launch_bounds__(256) void k_gemm_argmin(
    const unsigned short* __restrict__ Ah, const unsigned short* __restrict__ Bh,
    const float* __restrict__ wnorm, uint2* __restrict__ pout) {
    __shared__ unsigned short As[128 * 256];   // 64 KB, 16B-chunk pos = c ^ (row&7)
    __shared__ unsigned short Bs[128 * 32];    // 8 KB,  16B-chunk pos = c ^ (row&3)

    int tid  = threadIdx.x;
    int wave = tid >> 6, lane = tid & 63;
    int g16  = lane >> 4, r16 = lane & 15;
    int n0   = blockIdx.x * 128;
    int strip = blockIdx.y;

    // ---- stage full A tile (128 x 256 bf16) via global_load_lds ----
    #pragma unroll
    for (int i = 0; i < 16; ++i) {
        int s = (wave * 16 + i) * 64 + lane;
        int row = s >> 5, pos = s & 31;
        int c = pos ^ (row & 7);
        const unsigned int* ga = (const unsigned int*)(Ah + (size_t)(n0 + row) * 256 + c * 8);
        unsigned int* la = (unsigned int*)&As[(size_t)((wave * 16 + i) * 64) * 8];
        __builtin_amdgcn_global_load_lds((const __attribute__((address_space(1))) unsigned int*)ga,
                                         (__attribute__((address_space(3))) unsigned int*)la, 16, 0, 0);
    }

    unsigned int b1[16], b2[16];
    #pragma unroll
    for (int i = 0; i < 16; ++i) { b1[i] = 0xFFFFFFFFu; b2[i] = 0xFFFFFFFFu; }

    for (int kbi = 0; kbi < KB_PER; ++kbi) {
        int kb = strip * KB_PER + kbi;
        int c0 = kb * 128;

        f32x4 acc[4][4];
        #pragma unroll
        for (int mt = 0; mt < 4; ++mt)
            #pragma unroll
            for (int nt = 0; nt < 4; ++nt)
                acc[mt][nt] = (f32x4){0.f, 0.f, 0.f, 0.f};

        for (int ks = 0; ks < 8; ++ks) {
            __syncthreads();
            #pragma unroll
            for (int j = 0; j < 2; ++j) {
                int s = (wave * 2 + j) * 64 + lane;
                int m = s >> 2, pk = (s & 3) ^ (m & 3);
                const unsigned int* gb = (const unsigned int*)(Bh + (size_t)(c0 + m) * 256 + ks * 32 + pk * 8);
                unsigned int* lb = (unsigned int*)&Bs[(size_t)((wave * 2 + j) * 64) * 8];
                __builtin_amdgcn_global_load_lds((const __attribute__((address_space(1))) unsigned int*)gb,
                                                 (__attribute__((address_space(3))) unsigned int*)lb, 16, 0, 0);
            }
            __syncthreads();
            bf16x8 af[4], bfr[4];
            #pragma unroll
            for (int mt = 0; mt < 4; ++mt) {
                int row = (wave >> 1) * 64 + mt * 16 + r16;
                int pos = (ks * 4 + g16) ^ (row & 7);
                af[mt] = *(const bf16x8*)&As[(row * 32 + pos) * 8];
            }
            #pragma unroll
            for (int nt = 0; nt < 4; ++nt) {
                int row = (wave & 1) * 64 + nt * 16 + r16;
                int pk = g16 ^ (row & 3);
                bfr[nt] = *(const bf16x8*)&Bs[(row * 4 + pk) * 8];
            }
            #pragma unroll
            for (int mt = 0; mt < 4; ++mt)
                #pragma unroll
                for (int nt = 0; nt < 4; ++nt)
                    acc[mt][nt] = __builtin_amdgcn_mfma_f32_16x16x32_bf16(af[mt], bfr[nt], acc[mt][nt], 0, 0, 0);
        }

        // per-kb scoring: 5 ops/score into per-(mt,rg) top-2
        float wnb[4];
        unsigned int orv[4];
        #pragma unroll
        for (int nt = 0; nt < 4; ++nt) {
            int code = c0 + (wave & 1) * 64 + nt * 16 + r16;
            wnb[nt] = wnorm[code] + 0.0625f;
            orv[nt] = (unsigned int)((kbi << 7) | ((wave & 1) << 6) | (nt << 4));
        }
        #pragma unroll
        for (int mt = 0; mt < 4; ++mt)
            #pragma unroll
            for (int rg = 0; rg < 4; ++rg) {
                int i = mt * 4 + rg;
                #pragma unroll
                for (int nt = 0; nt < 4; ++nt) {
                    float s = fmaf(-2.0f, acc[mt][nt][rg], wnb[nt]);
                    unsigned int u = (__float_as_uint(s) & 0xFFFFF800u) | orv[nt];
                    unsigned int t = b1[i] > u ? b1[i] : u;
                    b1[i] = b1[i] < u ? b1[i] : u;
                    b2[i] = b2[i] < t ? b2[i] : t;
                }
            }
    }

    // attach r16, 16-lane shuffle top-2 merge
    #pragma unroll
    for (int i = 0; i < 16; ++i) {
        unsigned int v1 = b1[i] | (unsigned int)r16;
        unsigned int v2 = b2[i] | (unsigned int)r16;
        #pragma unroll
        for (int off = 1; off < 16; off <<= 1) {
            unsigned int o1 = __shfl_xor((int)v1, off);
            unsigned int o2 = __shfl_xor((int)v2, off);
            unsigned int n1 = v1 < o1 ? v1 : o1;
            unsigned int hi = v1 < o1 ? o1 : v1;
            unsigned int lo = v2 < o2 ? v2 : o2;
            v1 = n1;
            v2 = hi < lo ? hi : lo;
        }
        b1[i] = v1; b2[i] = v2;
    }

    __syncthreads();                 // all Bs reads done; reuse as reduction buffer
    unsigned int* red1 = (unsigned int*)Bs;        // [2][128]
    unsigned int* red2 = red1 + 256;
    if (r16 == 0) {
        #pragma unroll
        for (int mt = 0; mt < 4; ++mt)
            #pragma unroll
            for (int rg = 0; rg < 4; ++rg) {
                int row = (wave >> 1) * 64 + mt * 16 + g16 * 4 + rg;
                red1[(wave & 1) * 128 + row] = b1[mt * 4 + rg];
                red2[(wave & 1) * 128 + row] = b2[mt * 4 + rg];
            }
    }
    __syncthreads();
    if (tid < 128) {
        unsigned int a1 = red1[tid], a2 = red2[tid];
        unsigned int c1 = red1[128 + tid], c2 = red2[128 + tid];
        unsigned int m1 = a1 < c1 ? a1 : c1;
        unsigned int hi = a1 < c1 ? c1 : a1;
        unsigned int lo = a2 < c2 ? a2 : c2;
        pout[(size_t)strip * N_TOK + n0 + tid] = make_uint2(m1, hi < lo ? hi : lo);
    }
}

// ---- K4: merge strips + exact rescore + token + counts/sumsq/embed scatter ----
__global__ void k_select(const uint2* __restrict__ pout, const float* __restrict__ zf,
                         const float* __restrict__ w, int* __restrict__ token,
                         float* __restrict__ counts, float* __restrict__ o_embed,
                         float* __restrict__ scal) {
    int n = blockIdx.x * 4 + (threadIdx.x >> 6);
    int lane = threadIdx.x & 63;
    unsigned int c1 = 0xFFFFFFFFu, c2 = 0xFFFFFFFFu;
    int s1 = 0, s2 = 0;
    #pragma unroll
    for (int s = 0; s < STRIPS; ++s) {
        uint2 p = pout[(size_t)s * N_TOK + n];
        if (p.x < c1)      { c2 = c1; s2 = s1; c1 = p.x; s1 = s; }
        else if (p.x < c2) { c2 = p.x; s2 = s; }
        if (p.y < c1)      { c2 = c1; s2 = s1; c1 = p.y; s1 = s; }
        else if (p.y < c2) { c2 = p.y; s2 = s; }
    }
    int code1 = (s1 << 11) | (int)(c1 & 0x7FFu);
    int code2 = (s2 << 11) | (int)(c2 & 0x7FFu);

    float4 zv = ((const float4*)(zf + (size_t)n * DIM))[lane];
    float4 w1 = ((const float4*)(w + (size_t)code1 * DIM))[lane];
    float4 w2 = ((const float4*)(w + (size_t)code2 * DIM))[lane];
    float ax = zv.x - w1.x, ay = zv.y - w1.y, az = zv.z - w1.z, aw = zv.w - w1.w;
    float bx = zv.x - w2.x, by = zv.y - w2.y, bz = zv.z - w2.z, bw = zv.w - w2.w;
    float d1 = ax * ax + ay * ay + az * az + aw * aw;
    float d2 = bx * bx + by * by + bz * bz + bw * bw;
    d1 = wave_reduce_sum(d1);
    d2 = wave_reduce_sum(d2);
    d1 = __shfl(d1, 0); d2 = __shfl(d2, 0);
    bool take2 = (d2 < d1) || (d2 == d1 && code2 < code1);
    int tok = take2 ? code2 : code1;
    if (lane == 0) {
        token[n] = tok;
        atomicAdd(&scal[0], take2 ? d2 : d1);
        atomicAdd(&counts[tok], 1.0f);
    }
    float* ed = o_embed + (size_t)tok * DIM + lane * 4;
    atomicAdd(ed + 0, ONE_M_DECAY * zv.x);
    atomicAdd(ed + 1, ONE_M_DECAY * zv.y);
    atomicAdd(ed + 2, ONE_M_DECAY * zv.z);
    atomicAdd(ed + 3, ONE_M_DECAY * zv.w);
}

// ---- K_init: embed_avg_new = DECAY * embed_avg ----
__global__ void k_init_embed(const float* __restrict__ ea, float* __restrict__ o_embed) {
    int i = blockIdx.x * 256 + threadIdx.x;
    float4 v = ((const float4*)ea)[i];
    ((float4*)o_embed)[i] = make_float4(DECAYF * v.x, DECAYF * v.y, DECAYF * v.z, DECAYF * v.w);
}

// ---- K5: out[b][c][hw] = weight[token[b*HW+hw]][c] ----
__global__ void k_write_out(const int* __restrict__ token, const float* __restrict__ w,
                            float* __restrict__ out) {
    __shared__ float t[32][33];
    __shared__ int tok[32];
    int b = blockIdx.z, c0 = blockIdx.y * 32, h0 = blockIdx.x * 32;
    int tid = threadIdx.x, jx = tid & 31, iy = tid >> 5;
    if (tid < 32) tok[tid] = token[b * HW + h0 + tid];
    __syncthreads();
    #pragma unroll
    for (int p = 0; p < 4; ++p) {
        int hh = iy + p * 8;
        t[hh][jx] = w[(size_t)tok[hh] * DIM + c0 + jx];
    }
    __syncthreads();
    #pragma unroll
    for (int p = 0; p < 4; ++p) {
        int cc = iy + p * 8;
        out[(size_t)b * DIM * HW + (size_t)(c0 + cc) * HW + h0 + jx] = t[jx][cc];
    }
}

// ---- K6: cluster_new + reductions ----
__global__ void k_cluster(const float* __restrict__ cs, const float* __restrict__ counts,
                          float* __restrict__ o_cluster, float* __restrict__ scal) {
    int k = blockIdx.x * 256 + threadIdx.x;
    int lane = threadIdx.x & 63;
    float cnt = counts[k];
    float cn = DECAYF * cs[k] + ONE_M_DECAY * cnt;
    o_cluster[k] = cn;
    float used = cnt > 0.f ? 1.f : 0.f;
    float p = cnt * (1.0f / 16384.0f);
    float pl = p * logf(p + 1e-10f);
    cn   = wave_reduce_sum(cn);
    used = wave_reduce_sum(used);
    pl   = wave_reduce_sum(pl);
    if (lane == 0) {
        atomicAdd(&scal[1], cn);
        atomicAdd(&scal[2], used);
        atomicAdd(&scal[3], pl);
    }
}

// ---- K7: scalar outputs ----
__global__ void k_scalars(const float* __restrict__ scal, float* __restrict__ o_scal) {
    if (threadIdx.x == 0) {
        float sumsq = scal[0], used = scal[2], plogp = scal[3];
        o_scal[0] = BETAF * sumsq / (float)(N_TOK * DIM);
        o_scal[1] = sumsq / (float)N_TOK;
        o_scal[2] = used * (1.0f / (float)KCB);
        o_scal[3] = expf(-plogp);
    }
}

// ---- K8: weight_new ----
__global__ void k_weight_new(const float* __restrict__ o_embed, const float* __restrict__ o_cluster,
                             const float* __restrict__ scal, float* __restrict__ o_wnew) {
    int i4 = blockIdx.x * 256 + threadIdx.x;
    int k = i4 >> 6;
    float ntot = scal[1];
    float sm = (o_cluster[k] + EPSF) / (ntot + (float)KCB * EPSF) * ntot;
    float4 v = ((const float4*)o_embed)[i4];
    ((float4*)o_wnew)[i4] = make_float4(v.x / sm, v.y / sm, v.z / sm, v.w / sm);
}

extern "C" void kernel_launch(void* const* d_in, const int* in_sizes, int n_in,
                              void* d_out, int out_size, void* d_ws, size_t ws_size,
                              hipStream_t stream) {
    const float* z  = (const float*)d_in[0];
    const float* w  = (const float*)d_in[1];
    const float* cs = (const float*)d_in[2];
    const float* ea = (const float*)d_in[3];
    float* out = (float*)d_out;

    char* w8 = (char*)d_ws;
    unsigned short* Ah = (unsigned short*)(w8 + 0);         //  8 MB
    unsigned short* Bh = (unsigned short*)(w8 + 8388608);   //  8 MB
    uint2* pout  = (uint2*)(w8 + 16777216);                 //  1 MB
    float* wnorm  = (float*)(w8 + 17825792);
    int*   token  = (int*)(w8 + 17891328);
    float* counts = (float*)(w8 + 17956864);
    float* scal   = (float*)(w8 + 18022400);

    // zf aliased into d_out (overwritten only at k_write_out, after all zf reads)
    float* zf = out;
    float* o_scal    = out + 4194304;
    float* o_wnew    = out + 4194308;
    float* o_cluster = out + 8388612;
    float* o_embed   = out + 8404996;

    hipMemsetAsync(counts, 0, 65536 + 64, stream);  // counts + scal
    k_transpose_z<<<dim3(32, 8, 16), 256, 0, stream>>>(z, zf, Ah);
    k_prep_w<<<4096, 256, 0, stream>>>(w, Bh, wnorm);
    k_init_embed<<<4096, 256, 0, stream>>>(ea, o_embed);
    k_gemm_argmin<<<dim3(128, STRIPS), 256, 0, stream>>>(Ah, Bh, wnorm, pout);
    k_select<<<4096, 256, 0, stream>>>(pout, zf, w, token, counts, o_embed, scal);
    k_write_out<<<dim3(32, 8, 16), 256, 0, stream>>>(token, w, out);
    k_cluster<<<64, 256, 0, stream>>>(cs, counts, o_cluster, scal);
    k_scalars<<<1, 64, 0, stream>>>(scal, o_scal);
    k_weight_new<<<4096, 256, 0, stream>>>(o_embed, o_cluster, scal, o_wnew);
}

// Round 5
// 531.668 us; speedup vs baseline: 8.3807x; 1.0020x over previous
//
#include <hip/hip_runtime.h>

#define N_TOK 16384
#define KCB   16384
#define DIM   256
#define HW    1024
#define DECAYF 0.8f
#define ONE_M_DECAY 0.2f
#define BETAF 0.25f
#define EPSF  1e-5f
#define STRIPS 8
#define KB_PER 16

typedef __attribute__((ext_vector_type(8))) short bf16x8;
typedef __attribute__((ext_vector_type(4))) float f32x4;

__device__ __forceinline__ float wave_reduce_sum(float s) {
    #pragma unroll
    for (int o = 32; o > 0; o >>= 1) s += __shfl_down(s, o);
    return s;
}

__device__ __forceinline__ unsigned short f2bf(float x) {
    union { float f; unsigned int u; } a; a.f = x;
    unsigned int r = a.u + 0x7fffu + ((a.u >> 16) & 1u);
    return (unsigned short)(r >> 16);
}

// ---- K1: transpose z[b][c][hw] -> zf[n][d] (fp32) + Ah[n][d] (bf16) ----
__global__ void k_transpose_z(const float* __restrict__ z, float* __restrict__ zf,
                              unsigned short* __restrict__ Ah) {
    __shared__ float t[32][33];
    int b  = blockIdx.z;
    int c0 = blockIdx.y * 32;
    int h0 = blockIdx.x * 32;
    int tid = threadIdx.x;
    int jx = tid & 31, iy = tid >> 5;
    const float* zb = z + (size_t)b * DIM * HW;
    #pragma unroll
    for (int p = 0; p < 4; ++p) {
        int ci = iy + p * 8;
        t[ci][jx] = zb[(size_t)(c0 + ci) * HW + h0 + jx];
    }
    __syncthreads();
    #pragma unroll
    for (int p = 0; p < 4; ++p) {
        int hh = iy + p * 8;
        size_t idx = (size_t)(b * HW + h0 + hh) * DIM + c0 + jx;
        float v = t[jx][hh];
        zf[idx] = v;
        Ah[idx] = f2bf(v);
    }
}

// ---- K2: Bh[k][d] = bf16(w), wnorm[k] = |w_k|^2 ----
__global__ void k_prep_w(const float* __restrict__ w, unsigned short* __restrict__ Bh,
                         float* __restrict__ wnorm) {
    int wv = blockIdx.x * 4 + (threadIdx.x >> 6);
    int lane = threadIdx.x & 63;
    float4 v = ((const float4*)(w + (size_t)wv * DIM))[lane];
    ushort4 h;
    h.x = f2bf(v.x); h.y = f2bf(v.y); h.z = f2bf(v.z); h.w = f2bf(v.w);
    ((ushort4*)(Bh + (size_t)wv * DIM))[lane] = h;
    float s = v.x * v.x + v.y * v.y + v.z * v.z + v.w * v.w;
    s = wave_reduce_sum(s);
    if (lane == 0) wnorm[wv] = s;
}

// ---- K2b: scal[1] = sum(cluster_size) ----
__global__ void k_sum_cs(const float* __restrict__ cs, float* __restrict__ scal) {
    int i = blockIdx.x * 256 + threadIdx.x;
    int lane = threadIdx.x & 63;
    float v = cs[i];
    v = wave_reduce_sum(v);
    if (lane == 0) atomicAdd(&scal[1], v);
}

// ---- K3: bf16 MFMA GEMM, A-resident, in-kernel kb sweep, packed-u32 top-2 ----
__global__ __launch_bounds__(256) void k_gemm_argmin(
    const unsigned short* __restrict__ Ah, const unsigned short* __restrict__ Bh,
    const float* __restrict__ wnorm, uint2* __restrict__ pout) {
    __shared__ unsigned short As[128 * 256];   // 64 KB, 16B-chunk pos = c ^ (row&7)
    __shared__ unsigned short Bs[128 * 32];    // 8 KB,  16B-chunk pos = c ^ (row&3)

    int tid  = threadIdx.x;
    int wave = tid >> 6, lane = tid & 63;
    int g16  = lane >> 4, r16 = lane & 15;
    int n0   = blockIdx.x * 128;
    int strip = blockIdx.y;

    #pragma unroll
    for (int i = 0; i < 16; ++i) {
        int s = (wave * 16 + i) * 64 + lane;
        int row = s >> 5, pos = s & 31;
        int c = pos ^ (row & 7);
        const unsigned int* ga = (const unsigned int*)(Ah + (size_t)(n0 + row) * 256 + c * 8);
        unsigned int* la = (unsigned int*)&As[(size_t)((wave * 16 + i) * 64) * 8];
        __builtin_amdgcn_global_load_lds((const __attribute__((address_space(1))) unsigned int*)ga,
                                         (__attribute__((address_space(3))) unsigned int*)la, 16, 0, 0);
    }

    unsigned int b1[16], b2[16];
    #pragma unroll
    for (int i = 0; i < 16; ++i) { b1[i] = 0xFFFFFFFFu; b2[i] = 0xFFFFFFFFu; }

    for (int kbi = 0; kbi < KB_PER; ++kbi) {
        int kb = strip * KB_PER + kbi;
        int c0 = kb * 128;

        f32x4 acc[4][4];
        #pragma unroll
        for (int mt = 0; mt < 4; ++mt)
            #pragma unroll
            for (int nt = 0; nt < 4; ++nt)
                acc[mt][nt] = (f32x4){0.f, 0.f, 0.f, 0.f};

        for (int ks = 0; ks < 8; ++ks) {
            __syncthreads();
            #pragma unroll
            for (int j = 0; j < 2; ++j) {
                int s = (wave * 2 + j) * 64 + lane;
                int m = s >> 2, pk = (s & 3) ^ (m & 3);
                const unsigned int* gb = (const unsigned int*)(Bh + (size_t)(c0 + m) * 256 + ks * 32 + pk * 8);
                unsigned int* lb = (unsigned int*)&Bs[(size_t)((wave * 2 + j) * 64) * 8];
                __builtin_amdgcn_global_load_lds((const __attribute__((address_space(1))) unsigned int*)gb,
                                                 (__attribute__((address_space(3))) unsigned int*)lb, 16, 0, 0);
            }
            __syncthreads();
            bf16x8 af[4], bfr[4];
            #pragma unroll
            for (int mt = 0; mt < 4; ++mt) {
                int row = (wave >> 1) * 64 + mt * 16 + r16;
                int pos = (ks * 4 + g16) ^ (row & 7);
                af[mt] = *(const bf16x8*)&As[(row * 32 + pos) * 8];
            }
            #pragma unroll
            for (int nt = 0; nt < 4; ++nt) {
                int row = (wave & 1) * 64 + nt * 16 + r16;
                int pk = g16 ^ (row & 3);
                bfr[nt] = *(const bf16x8*)&Bs[(row * 4 + pk) * 8];
            }
            #pragma unroll
            for (int mt = 0; mt < 4; ++mt)
                #pragma unroll
                for (int nt = 0; nt < 4; ++nt)
                    acc[mt][nt] = __builtin_amdgcn_mfma_f32_16x16x32_bf16(af[mt], bfr[nt], acc[mt][nt], 0, 0, 0);
        }

        float wnb[4];
        unsigned int orv[4];
        #pragma unroll
        for (int nt = 0; nt < 4; ++nt) {
            int code = c0 + (wave & 1) * 64 + nt * 16 + r16;
            wnb[nt] = wnorm[code] + 0.0625f;
            orv[nt] = (unsigned int)((kbi << 7) | ((wave & 1) << 6) | (nt << 4));
        }
        #pragma unroll
        for (int mt = 0; mt < 4; ++mt)
            #pragma unroll
            for (int rg = 0; rg < 4; ++rg) {
                int i = mt * 4 + rg;
                #pragma unroll
                for (int nt = 0; nt < 4; ++nt) {
                    float s = fmaf(-2.0f, acc[mt][nt][rg], wnb[nt]);
                    unsigned int u = (__float_as_uint(s) & 0xFFFFF800u) | orv[nt];
                    unsigned int t = b1[i] > u ? b1[i] : u;
                    b1[i] = b1[i] < u ? b1[i] : u;
                    b2[i] = b2[i] < t ? b2[i] : t;
                }
            }
    }

    #pragma unroll
    for (int i = 0; i < 16; ++i) {
        unsigned int v1 = b1[i] | (unsigned int)r16;
        unsigned int v2 = b2[i] | (unsigned int)r16;
        #pragma unroll
        for (int off = 1; off < 16; off <<= 1) {
            unsigned int o1 = __shfl_xor((int)v1, off);
            unsigned int o2 = __shfl_xor((int)v2, off);
            unsigned int n1 = v1 < o1 ? v1 : o1;
            unsigned int hi = v1 < o1 ? o1 : v1;
            unsigned int lo = v2 < o2 ? v2 : o2;
            v1 = n1;
            v2 = hi < lo ? hi : lo;
        }
        b1[i] = v1; b2[i] = v2;
    }

    __syncthreads();
    unsigned int* red1 = (unsigned int*)Bs;
    unsigned int* red2 = red1 + 256;
    if (r16 == 0) {
        #pragma unroll
        for (int mt = 0; mt < 4; ++mt)
            #pragma unroll
            for (int rg = 0; rg < 4; ++rg) {
                int row = (wave >> 1) * 64 + mt * 16 + g16 * 4 + rg;
                red1[(wave & 1) * 128 + row] = b1[mt * 4 + rg];
                red2[(wave & 1) * 128 + row] = b2[mt * 4 + rg];
            }
    }
    __syncthreads();
    if (tid < 128) {
        unsigned int a1 = red1[tid], a2 = red2[tid];
        unsigned int c1 = red1[128 + tid], c2 = red2[128 + tid];
        unsigned int m1 = a1 < c1 ? a1 : c1;
        unsigned int hi = a1 < c1 ? c1 : a1;
        unsigned int lo = a2 < c2 ? a2 : c2;
        pout[(size_t)strip * N_TOK + n0 + tid] = make_uint2(m1, hi < lo ? hi : lo);
    }
}

// ---- K4: merge strips + exact rescore -> (token, rank); counts++, sumsq ----
__global__ void k_select(const uint2* __restrict__ pout, const float* __restrict__ zf,
                         const float* __restrict__ w, int2* __restrict__ tokrank,
                         float* __restrict__ counts, float* __restrict__ scal) {
    int n = blockIdx.x * 4 + (threadIdx.x >> 6);
    int lane = threadIdx.x & 63;
    unsigned int c1 = 0xFFFFFFFFu, c2 = 0xFFFFFFFFu;
    int s1 = 0, s2 = 0;
    #pragma unroll
    for (int s = 0; s < STRIPS; ++s) {
        uint2 p = pout[(size_t)s * N_TOK + n];
        if (p.x < c1)      { c2 = c1; s2 = s1; c1 = p.x; s1 = s; }
        else if (p.x < c2) { c2 = p.x; s2 = s; }
        if (p.y < c1)      { c2 = c1; s2 = s1; c1 = p.y; s1 = s; }
        else if (p.y < c2) { c2 = p.y; s2 = s; }
    }
    int code1 = (s1 << 11) | (int)(c1 & 0x7FFu);
    int code2 = (s2 << 11) | (int)(c2 & 0x7FFu);

    float4 zv = ((const float4*)(zf + (size_t)n * DIM))[lane];
    float4 w1 = ((const float4*)(w + (size_t)code1 * DIM))[lane];
    float4 w2 = ((const float4*)(w + (size_t)code2 * DIM))[lane];
    float ax = zv.x - w1.x, ay = zv.y - w1.y, az = zv.z - w1.z, aw = zv.w - w1.w;
    float bx = zv.x - w2.x, by = zv.y - w2.y, bz = zv.z - w2.z, bw = zv.w - w2.w;
    float d1 = ax * ax + ay * ay + az * az + aw * aw;
    float d2 = bx * bx + by * by + bz * bz + bw * bw;
    d1 = wave_reduce_sum(d1);
    d2 = wave_reduce_sum(d2);
    if (lane == 0) {
        bool take2 = (d2 < d1) || (d2 == d1 && code2 < code1);
        int tok = take2 ? code2 : code1;
        atomicAdd(&scal[0], take2 ? d2 : d1);
        float old = atomicAdd(&counts[tok], 1.0f);
        tokrank[n] = make_int2(tok, (int)old);
    }
}

// ---- K5: single-block exclusive prefix sum of counts -> offsets ----
__global__ void k_scan(const float* __restrict__ counts, int* __restrict__ offsets) {
    int tid = threadIdx.x;                 // 256 threads, 64 codes each
    int lane = tid & 63, wv = tid >> 6;
    int base = tid * 64;
    int sum = 0;
    for (int i = 0; i < 64; ++i) sum += (int)counts[base + i];
    int x = sum;
    #pragma unroll
    for (int o = 1; o < 64; o <<= 1) {
        int y = __shfl_up(x, o);
        if (lane >= o) x += y;
    }
    __shared__ int wt[4];
    if (lane == 63) wt[wv] = x;
    __syncthreads();
    int wbase = 0;
    for (int i = 0; i < wv; ++i) wbase += wt[i];
    int run = wbase + x - sum;             // exclusive base for this thread's chunk
    for (int i = 0; i < 64; ++i) {
        offsets[base + i] = run;
        run += (int)counts[base + i];
    }
}

// ---- K6: perm[offsets[tok] + rank] = n ----
__global__ void k_scatter(const int2* __restrict__ tokrank, const int* __restrict__ offsets,
                          int* __restrict__ perm) {
    int n = blockIdx.x * 256 + threadIdx.x;
    int2 tr = tokrank[n];
    perm[offsets[tr.x] + tr.y] = n;
}

// ---- K7: one wave per code: gather z rows, emit embed_avg_new/cluster_new/weight_new ----
__global__ void k_embed(const int* __restrict__ offsets, const float* __restrict__ counts,
                        const int* __restrict__ perm, const float* __restrict__ zf,
                        const float* __restrict__ ea, const float* __restrict__ cs,
                        const float* __restrict__ scal, float* __restrict__ o_embed,
                        float* __restrict__ o_cluster, float* __restrict__ o_wnew) {
    int k = blockIdx.x * 4 + (threadIdx.x >> 6);
    int lane = threadIdx.x & 63;
    int off = offsets[k];
    int c = (int)counts[k];
    float4 acc = make_float4(0.f, 0.f, 0.f, 0.f);
    for (int i = 0; i < c; ++i) {
        int n = perm[off + i];
        float4 zv = ((const float4*)(zf + (size_t)n * DIM))[lane];
        acc.x += zv.x; acc.y += zv.y; acc.z += zv.z; acc.w += zv.w;
    }
    float4 eav = ((const float4*)(ea + (size_t)k * DIM))[lane];
    float4 em = make_float4(DECAYF * eav.x + ONE_M_DECAY * acc.x,
                            DECAYF * eav.y + ONE_M_DECAY * acc.y,
                            DECAYF * eav.z + ONE_M_DECAY * acc.z,
                            DECAYF * eav.w + ONE_M_DECAY * acc.w);
    ((float4*)(o_embed + (size_t)k * DIM))[lane] = em;
    float cn = DECAYF * cs[k] + ONE_M_DECAY * (float)c;
    float ntot = DECAYF * scal[1] + ONE_M_DECAY * (float)N_TOK;  // sum(cluster_new) analytic
    float sm = (cn + EPSF) / (ntot + (float)KCB * EPSF) * ntot;
    float inv = 1.0f / sm;
    ((float4*)(o_wnew + (size_t)k * DIM))[lane] =
        make_float4(em.x * inv, em.y * inv, em.z * inv, em.w * inv);
    if (lane == 0) o_cluster[k] = cn;
}

// ---- K8: out[b][c][hw] = weight[token[b*HW+hw]][c] ----
__global__ void k_write_out(const int2* __restrict__ tokrank, const float* __restrict__ w,
                            float* __restrict__ out) {
    __shared__ float t[32][33];
    __shared__ int tok[32];
    int b = blockIdx.z, c0 = blockIdx.y * 32, h0 = blockIdx.x * 32;
    int tid = threadIdx.x, jx = tid & 31, iy = tid >> 5;
    if (tid < 32) tok[tid] = tokrank[b * HW + h0 + tid].x;
    __syncthreads();
    #pragma unroll
    for (int p = 0; p < 4; ++p) {
        int hh = iy + p * 8;
        t[hh][jx] = w[(size_t)tok[hh] * DIM + c0 + jx];
    }
    __syncthreads();
    #pragma unroll
    for (int p = 0; p < 4; ++p) {
        int cc = iy + p * 8;
        out[(size_t)b * DIM * HW + (size_t)(c0 + cc) * HW + h0 + jx] = t[jx][cc];
    }
}

// ---- K9: used / plogp reductions ----
__global__ void k_stats(const float* __restrict__ counts, float* __restrict__ scal) {
    int k = blockIdx.x * 256 + threadIdx.x;
    int lane = threadIdx.x & 63;
    float cnt = counts[k];
    float used = cnt > 0.f ? 1.f : 0.f;
    float p = cnt * (1.0f / 16384.0f);
    float pl = p * logf(p + 1e-10f);
    used = wave_reduce_sum(used);
    pl   = wave_reduce_sum(pl);
    if (lane == 0) {
        atomicAdd(&scal[2], used);
        atomicAdd(&scal[3], pl);
    }
}

// ---- K10: scalar outputs ----
__global__ void k_scalars(const float* __restrict__ scal, float* __restrict__ o_scal) {
    if (threadIdx.x == 0) {
        float sumsq = scal[0], used = scal[2], plogp = scal[3];
        o_scal[0] = BETAF * sumsq / (float)(N_TOK * DIM);
        o_scal[1] = sumsq / (float)N_TOK;
        o_scal[2] = used * (1.0f / (float)KCB);
        o_scal[3] = expf(-plogp);
    }
}

extern "C" void kernel_launch(void* const* d_in, const int* in_sizes, int n_in,
                              void* d_out, int out_size, void* d_ws, size_t ws_size,
                              hipStream_t stream) {
    const float* z  = (const float*)d_in[0];
    const float* w  = (const float*)d_in[1];
    const float* cs = (const float*)d_in[2];
    const float* ea = (const float*)d_in[3];
    float* out = (float*)d_out;

    char* w8 = (char*)d_ws;
    unsigned short* Ah = (unsigned short*)(w8 + 0);          //  8 MB
    unsigned short* Bh = (unsigned short*)(w8 + 8388608);    //  8 MB
    float* wnorm   = (float*)(w8 + 16777216);                // 64 KB
    int2*  tokrank = (int2*)(w8 + 16842752);                 // 128 KB
    float* counts  = (float*)(w8 + 16973824);                // 64 KB (zeroed)
    int*   offsets = (int*)(w8 + 17039360);                  // 64 KB
    int*   perm    = (int*)(w8 + 17104896);                  // 64 KB
    float* scal    = (float*)(w8 + 17170432);                // 64 B (zeroed)

    // aliased into d_out, finalized later in the launch:
    float* zf = out;                                   // bytes [0,16MB): overwritten by k_write_out
    uint2* pout = (uint2*)(out + 4194308);             // 1 MB inside o_wnew; consumed by k_select
    float* o_scal    = out + 4194304;
    float* o_wnew    = out + 4194308;
    float* o_cluster = out + 8388612;
    float* o_embed   = out + 8404996;

    hipMemsetAsync(counts, 0, 17170432 + 64 - 16973824, stream);  // counts..scal
    k_transpose_z<<<dim3(32, 8, 16), 256, 0, stream>>>(z, zf, Ah);
    k_prep_w<<<4096, 256, 0, stream>>>(w, Bh, wnorm);
    k_sum_cs<<<64, 256, 0, stream>>>(cs, scal);
    k_gemm_argmin<<<dim3(128, STRIPS), 256, 0, stream>>>(Ah, Bh, wnorm, pout);
    k_select<<<4096, 256, 0, stream>>>(pout, zf, w, tokrank, counts, scal);
    k_scan<<<1, 256, 0, stream>>>(counts, offsets);
    k_scatter<<<64, 256, 0, stream>>>(tokrank, offsets, perm);
    k_embed<<<4096, 256, 0, stream>>>(offsets, counts, perm, zf, ea, cs, scal,
                                      o_embed, o_cluster, o_wnew);
    k_write_out<<<dim3(32, 8, 16), 256, 0, stream>>>(tokrank, w, out);
    k_stats<<<64, 256, 0, stream>>>(counts, scal);
    k_scalars<<<1, 64, 0, stream>>>(scal, o_scal);
}

// Round 6
// 331.768 us; speedup vs baseline: 13.4303x; 1.6025x over previous
//
#include <hip/hip_runtime.h>

#define N_TOK 16384
#define KCB   16384
#define DIM   256
#define HW    1024
#define DECAYF 0.8f
#define ONE_M_DECAY 0.2f
#define BETAF 0.25f
#define EPSF  1e-5f
#define STRIPS 8
#define KB_PER 16

typedef __attribute__((ext_vector_type(8))) short bf16x8;
typedef __attribute__((ext_vector_type(4))) float f32x4;

__device__ __forceinline__ float wave_reduce_sum(float s) {
    #pragma unroll
    for (int o = 32; o > 0; o >>= 1) s += __shfl_down(s, o);
    return s;
}

__device__ __forceinline__ unsigned short f2bf(float x) {
    union { float f; unsigned int u; } a; a.f = x;
    unsigned int r = a.u + 0x7fffu + ((a.u >> 16) & 1u);
    return (unsigned short)(r >> 16);
}

// ---- K1: transpose z[b][c][hw] -> zf[n][d] (fp32) + Ah[n][d] (bf16) ----
__global__ void k_transpose_z(const float* __restrict__ z, float* __restrict__ zf,
                              unsigned short* __restrict__ Ah) {
    __shared__ float t[32][33];
    int b  = blockIdx.z;
    int c0 = blockIdx.y * 32;
    int h0 = blockIdx.x * 32;
    int tid = threadIdx.x;
    int jx = tid & 31, iy = tid >> 5;
    const float* zb = z + (size_t)b * DIM * HW;
    #pragma unroll
    for (int p = 0; p < 4; ++p) {
        int ci = iy + p * 8;
        t[ci][jx] = zb[(size_t)(c0 + ci) * HW + h0 + jx];
    }
    __syncthreads();
    #pragma unroll
    for (int p = 0; p < 4; ++p) {
        int hh = iy + p * 8;
        size_t idx = (size_t)(b * HW + h0 + hh) * DIM + c0 + jx;
        float v = t[jx][hh];
        zf[idx] = v;
        Ah[idx] = f2bf(v);
    }
}

// ---- K2: Bh[k][d] = bf16(w), wnorm[k] = |w_k|^2 ----
__global__ void k_prep_w(const float* __restrict__ w, unsigned short* __restrict__ Bh,
                         float* __restrict__ wnorm) {
    int wv = blockIdx.x * 4 + (threadIdx.x >> 6);
    int lane = threadIdx.x & 63;
    float4 v = ((const float4*)(w + (size_t)wv * DIM))[lane];
    ushort4 h;
    h.x = f2bf(v.x); h.y = f2bf(v.y); h.z = f2bf(v.z); h.w = f2bf(v.w);
    ((ushort4*)(Bh + (size_t)wv * DIM))[lane] = h;
    float s = v.x * v.x + v.y * v.y + v.z * v.z + v.w * v.w;
    s = wave_reduce_sum(s);
    if (lane == 0) wnorm[wv] = s;
}

// ---- K2b: scal[1] = sum(cluster_size) ----
__global__ void k_sum_cs(const float* __restrict__ cs, float* __restrict__ scal) {
    int i = blockIdx.x * 256 + threadIdx.x;
    int lane = threadIdx.x & 63;
    float v = cs[i];
    v = wave_reduce_sum(v);
    if (lane == 0) atomicAdd(&scal[1], v);
}

// ---- K3: bf16 MFMA GEMM, A-resident, in-kernel kb sweep, packed-u32 top-2 ----
__global__ __launch_bounds__(256) void k_gemm_argmin(
    const unsigned short* __restrict__ Ah, const unsigned short* __restrict__ Bh,
    const float* __restrict__ wnorm, uint2* __restrict__ pout) {
    __shared__ unsigned short As[128 * 256];   // 64 KB, 16B-chunk pos = c ^ (row&7)
    __shared__ unsigned short Bs[128 * 32];    // 8 KB,  16B-chunk pos = c ^ (row&3)

    int tid  = threadIdx.x;
    int wave = tid >> 6, lane = tid & 63;
    int g16  = lane >> 4, r16 = lane & 15;
    int n0   = blockIdx.x * 128;
    int strip = blockIdx.y;

    #pragma unroll
    for (int i = 0; i < 16; ++i) {
        int s = (wave * 16 + i) * 64 + lane;
        int row = s >> 5, pos = s & 31;
        int c = pos ^ (row & 7);
        const unsigned int* ga = (const unsigned int*)(Ah + (size_t)(n0 + row) * 256 + c * 8);
        unsigned int* la = (unsigned int*)&As[(size_t)((wave * 16 + i) * 64) * 8];
        __builtin_amdgcn_global_load_lds((const __attribute__((address_space(1))) unsigned int*)ga,
                                         (__attribute__((address_space(3))) unsigned int*)la, 16, 0, 0);
    }

    unsigned int b1[16], b2[16];
    #pragma unroll
    for (int i = 0; i < 16; ++i) { b1[i] = 0xFFFFFFFFu; b2[i] = 0xFFFFFFFFu; }

    for (int kbi = 0; kbi < KB_PER; ++kbi) {
        int kb = strip * KB_PER + kbi;
        int c0 = kb * 128;

        f32x4 acc[4][4];
        #pragma unroll
        for (int mt = 0; mt < 4; ++mt)
            #pragma unroll
            for (int nt = 0; nt < 4; ++nt)
                acc[mt][nt] = (f32x4){0.f, 0.f, 0.f, 0.f};

        for (int ks = 0; ks < 8; ++ks) {
            __syncthreads();
            #pragma unroll
            for (int j = 0; j < 2; ++j) {
                int s = (wave * 2 + j) * 64 + lane;
                int m = s >> 2, pk = (s & 3) ^ (m & 3);
                const unsigned int* gb = (const unsigned int*)(Bh + (size_t)(c0 + m) * 256 + ks * 32 + pk * 8);
                unsigned int* lb = (unsigned int*)&Bs[(size_t)((wave * 2 + j) * 64) * 8];
                __builtin_amdgcn_global_load_lds((const __attribute__((address_space(1))) unsigned int*)gb,
                                                 (__attribute__((address_space(3))) unsigned int*)lb, 16, 0, 0);
            }
            __syncthreads();
            bf16x8 af[4], bfr[4];
            #pragma unroll
            for (int mt = 0; mt < 4; ++mt) {
                int row = (wave >> 1) * 64 + mt * 16 + r16;
                int pos = (ks * 4 + g16) ^ (row & 7);
                af[mt] = *(const bf16x8*)&As[(row * 32 + pos) * 8];
            }
            #pragma unroll
            for (int nt = 0; nt < 4; ++nt) {
                int row = (wave & 1) * 64 + nt * 16 + r16;
                int pk = g16 ^ (row & 3);
                bfr[nt] = *(const bf16x8*)&Bs[(row * 4 + pk) * 8];
            }
            #pragma unroll
            for (int mt = 0; mt < 4; ++mt)
                #pragma unroll
                for (int nt = 0; nt < 4; ++nt)
                    acc[mt][nt] = __builtin_amdgcn_mfma_f32_16x16x32_bf16(af[mt], bfr[nt], acc[mt][nt], 0, 0, 0);
        }

        float wnb[4];
        unsigned int orv[4];
        #pragma unroll
        for (int nt = 0; nt < 4; ++nt) {
            int code = c0 + (wave & 1) * 64 + nt * 16 + r16;
            wnb[nt] = wnorm[code] + 0.0625f;
            orv[nt] = (unsigned int)((kbi << 7) | ((wave & 1) << 6) | (nt << 4));
        }
        #pragma unroll
        for (int mt = 0; mt < 4; ++mt)
            #pragma unroll
            for (int rg = 0; rg < 4; ++rg) {
                int i = mt * 4 + rg;
                #pragma unroll
                for (int nt = 0; nt < 4; ++nt) {
                    float s = fmaf(-2.0f, acc[mt][nt][rg], wnb[nt]);
                    unsigned int u = (__float_as_uint(s) & 0xFFFFF800u) | orv[nt];
                    unsigned int t = b1[i] > u ? b1[i] : u;
                    b1[i] = b1[i] < u ? b1[i] : u;
                    b2[i] = b2[i] < t ? b2[i] : t;
                }
            }
    }

    #pragma unroll
    for (int i = 0; i < 16; ++i) {
        unsigned int v1 = b1[i] | (unsigned int)r16;
        unsigned int v2 = b2[i] | (unsigned int)r16;
        #pragma unroll
        for (int off = 1; off < 16; off <<= 1) {
            unsigned int o1 = __shfl_xor((int)v1, off);
            unsigned int o2 = __shfl_xor((int)v2, off);
            unsigned int n1 = v1 < o1 ? v1 : o1;
            unsigned int hi = v1 < o1 ? o1 : v1;
            unsigned int lo = v2 < o2 ? v2 : o2;
            v1 = n1;
            v2 = hi < lo ? hi : lo;
        }
        b1[i] = v1; b2[i] = v2;
    }

    __syncthreads();
    unsigned int* red1 = (unsigned int*)Bs;
    unsigned int* red2 = red1 + 256;
    if (r16 == 0) {
        #pragma unroll
        for (int mt = 0; mt < 4; ++mt)
            #pragma unroll
            for (int rg = 0; rg < 4; ++rg) {
                int row = (wave >> 1) * 64 + mt * 16 + g16 * 4 + rg;
                red1[(wave & 1) * 128 + row] = b1[mt * 4 + rg];
                red2[(wave & 1) * 128 + row] = b2[mt * 4 + rg];
            }
    }
    __syncthreads();
    if (tid < 128) {
        unsigned int a1 = red1[tid], a2 = red2[tid];
        unsigned int c1 = red1[128 + tid], c2 = red2[128 + tid];
        unsigned int m1 = a1 < c1 ? a1 : c1;
        unsigned int hi = a1 < c1 ? c1 : a1;
        unsigned int lo = a2 < c2 ? a2 : c2;
        pout[(size_t)strip * N_TOK + n0 + tid] = make_uint2(m1, hi < lo ? hi : lo);
    }
}

// ---- K4: merge strips + exact rescore -> (token, rank), dmin[n]; counts++ ----
__global__ void k_select(const uint2* __restrict__ pout, const float* __restrict__ zf,
                         const float* __restrict__ w, int2* __restrict__ tokrank,
                         float* __restrict__ counts, float* __restrict__ dmin) {
    int n = blockIdx.x * 4 + (threadIdx.x >> 6);
    int lane = threadIdx.x & 63;
    unsigned int c1 = 0xFFFFFFFFu, c2 = 0xFFFFFFFFu;
    int s1 = 0, s2 = 0;
    #pragma unroll
    for (int s = 0; s < STRIPS; ++s) {
        uint2 p = pout[(size_t)s * N_TOK + n];
        if (p.x < c1)      { c2 = c1; s2 = s1; c1 = p.x; s1 = s; }
        else if (p.x < c2) { c2 = p.x; s2 = s; }
        if (p.y < c1)      { c2 = c1; s2 = s1; c1 = p.y; s1 = s; }
        else if (p.y < c2) { c2 = p.y; s2 = s; }
    }
    int code1 = (s1 << 11) | (int)(c1 & 0x7FFu);
    int code2 = (s2 << 11) | (int)(c2 & 0x7FFu);

    float4 zv = ((const float4*)(zf + (size_t)n * DIM))[lane];
    float4 w1 = ((const float4*)(w + (size_t)code1 * DIM))[lane];
    float4 w2 = ((const float4*)(w + (size_t)code2 * DIM))[lane];
    float ax = zv.x - w1.x, ay = zv.y - w1.y, az = zv.z - w1.z, aw = zv.w - w1.w;
    float bx = zv.x - w2.x, by = zv.y - w2.y, bz = zv.z - w2.z, bw = zv.w - w2.w;
    float d1 = ax * ax + ay * ay + az * az + aw * aw;
    float d2 = bx * bx + by * by + bz * bz + bw * bw;
    d1 = wave_reduce_sum(d1);
    d2 = wave_reduce_sum(d2);
    if (lane == 0) {
        bool take2 = (d2 < d1) || (d2 == d1 && code2 < code1);
        int tok = take2 ? code2 : code1;
        dmin[n] = take2 ? d2 : d1;
        float old = atomicAdd(&counts[tok], 1.0f);
        tokrank[n] = make_int2(tok, (int)old);
    }
}

// ---- K5: single-block exclusive prefix sum of counts -> offsets ----
__global__ void k_scan(const float* __restrict__ counts, int* __restrict__ offsets) {
    int tid = threadIdx.x;                 // 256 threads, 64 codes each
    int lane = tid & 63, wv = tid >> 6;
    int base = tid * 64;
    int sum = 0;
    for (int i = 0; i < 64; ++i) sum += (int)counts[base + i];
    int x = sum;
    #pragma unroll
    for (int o = 1; o < 64; o <<= 1) {
        int y = __shfl_up(x, o);
        if (lane >= o) x += y;
    }
    __shared__ int wt[4];
    if (lane == 63) wt[wv] = x;
    __syncthreads();
    int wbase = 0;
    for (int i = 0; i < wv; ++i) wbase += wt[i];
    int run = wbase + x - sum;             // exclusive base for this thread's chunk
    for (int i = 0; i < 64; ++i) {
        offsets[base + i] = run;
        run += (int)counts[base + i];
    }
}

// ---- K6: perm[offsets[tok] + rank] = n ----
__global__ void k_scatter(const int2* __restrict__ tokrank, const int* __restrict__ offsets,
                          int* __restrict__ perm) {
    int n = blockIdx.x * 256 + threadIdx.x;
    int2 tr = tokrank[n];
    perm[offsets[tr.x] + tr.y] = n;
}

// ---- K7: one wave per code: gather z rows, emit embed_avg_new/cluster_new/weight_new ----
__global__ void k_embed(const int* __restrict__ offsets, const float* __restrict__ counts,
                        const int* __restrict__ perm, const float* __restrict__ zf,
                        const float* __restrict__ ea, const float* __restrict__ cs,
                        const float* __restrict__ scal, float* __restrict__ o_embed,
                        float* __restrict__ o_cluster, float* __restrict__ o_wnew) {
    int k = blockIdx.x * 4 + (threadIdx.x >> 6);
    int lane = threadIdx.x & 63;
    int off = offsets[k];
    int c = (int)counts[k];
    float4 acc = make_float4(0.f, 0.f, 0.f, 0.f);
    for (int i = 0; i < c; ++i) {
        int n = perm[off + i];
        float4 zv = ((const float4*)(zf + (size_t)n * DIM))[lane];
        acc.x += zv.x; acc.y += zv.y; acc.z += zv.z; acc.w += zv.w;
    }
    float4 eav = ((const float4*)(ea + (size_t)k * DIM))[lane];
    float4 em = make_float4(DECAYF * eav.x + ONE_M_DECAY * acc.x,
                            DECAYF * eav.y + ONE_M_DECAY * acc.y,
                            DECAYF * eav.z + ONE_M_DECAY * acc.z,
                            DECAYF * eav.w + ONE_M_DECAY * acc.w);
    ((float4*)(o_embed + (size_t)k * DIM))[lane] = em;
    float cn = DECAYF * cs[k] + ONE_M_DECAY * (float)c;
    float ntot = DECAYF * scal[1] + ONE_M_DECAY * (float)N_TOK;  // sum(cluster_new) analytic
    float sm = (cn + EPSF) / (ntot + (float)KCB * EPSF) * ntot;
    float inv = 1.0f / sm;
    ((float4*)(o_wnew + (size_t)k * DIM))[lane] =
        make_float4(em.x * inv, em.y * inv, em.z * inv, em.w * inv);
    if (lane == 0) o_cluster[k] = cn;
}

// ---- K8: out[b][c][hw] = weight[token[b*HW+hw]][c] ----
__global__ void k_write_out(const int2* __restrict__ tokrank, const float* __restrict__ w,
                            float* __restrict__ out) {
    __shared__ float t[32][33];
    __shared__ int tok[32];
    int b = blockIdx.z, c0 = blockIdx.y * 32, h0 = blockIdx.x * 32;
    int tid = threadIdx.x, jx = tid & 31, iy = tid >> 5;
    if (tid < 32) tok[tid] = tokrank[b * HW + h0 + tid].x;
    __syncthreads();
    #pragma unroll
    for (int p = 0; p < 4; ++p) {
        int hh = iy + p * 8;
        t[hh][jx] = w[(size_t)tok[hh] * DIM + c0 + jx];
    }
    __syncthreads();
    #pragma unroll
    for (int p = 0; p < 4; ++p) {
        int cc = iy + p * 8;
        out[(size_t)b * DIM * HW + (size_t)(c0 + cc) * HW + h0 + jx] = t[jx][cc];
    }
}

// ---- K9: used / plogp / sumsq reductions (256 atomics total) ----
__global__ void k_stats(const float* __restrict__ counts, const float* __restrict__ dmin,
                        float* __restrict__ scal) {
    int k = blockIdx.x * 256 + threadIdx.x;
    int lane = threadIdx.x & 63;
    float cnt = counts[k];
    float used = cnt > 0.f ? 1.f : 0.f;
    float p = cnt * (1.0f / 16384.0f);
    float pl = p * logf(p + 1e-10f);
    float dv = dmin[k];
    used = wave_reduce_sum(used);
    pl   = wave_reduce_sum(pl);
    dv   = wave_reduce_sum(dv);
    if (lane == 0) {
        atomicAdd(&scal[2], used);
        atomicAdd(&scal[3], pl);
        atomicAdd(&scal[0], dv);
    }
}

// ---- K10: scalar outputs ----
__global__ void k_scalars(const float* __restrict__ scal, float* __restrict__ o_scal) {
    if (threadIdx.x == 0) {
        float sumsq = scal[0], used = scal[2], plogp = scal[3];
        o_scal[0] = BETAF * sumsq / (float)(N_TOK * DIM);
        o_scal[1] = sumsq / (float)N_TOK;
        o_scal[2] = used * (1.0f / (float)KCB);
        o_scal[3] = expf(-plogp);
    }
}

extern "C" void kernel_launch(void* const* d_in, const int* in_sizes, int n_in,
                              void* d_out, int out_size, void* d_ws, size_t ws_size,
                              hipStream_t stream) {
    const float* z  = (const float*)d_in[0];
    const float* w  = (const float*)d_in[1];
    const float* cs = (const float*)d_in[2];
    const float* ea = (const float*)d_in[3];
    float* out = (float*)d_out;

    char* w8 = (char*)d_ws;
    unsigned short* Ah = (unsigned short*)(w8 + 0);          //  8 MB
    unsigned short* Bh = (unsigned short*)(w8 + 8388608);    //  8 MB
    float* wnorm   = (float*)(w8 + 16777216);                // 64 KB
    int2*  tokrank = (int2*)(w8 + 16842752);                 // 128 KB
    float* counts  = (float*)(w8 + 16973824);                // 64 KB (zeroed)
    int*   offsets = (int*)(w8 + 17039360);                  // 64 KB
    int*   perm    = (int*)(w8 + 17104896);                  // 64 KB
    float* scal    = (float*)(w8 + 17170432);                // 64 B (zeroed)
    float* dmin    = (float*)(w8 + 17170496);                // 64 KB

    // aliased into d_out, finalized later in the launch:
    float* zf = out;                                   // bytes [0,16MB): overwritten by k_write_out
    uint2* pout = (uint2*)(out + 4194308);             // 1 MB inside o_wnew; consumed by k_select
    float* o_scal    = out + 4194304;
    float* o_wnew    = out + 4194308;
    float* o_cluster = out + 8388612;
    float* o_embed   = out + 8404996;

    hipMemsetAsync(counts, 0, 17170432 + 64 - 16973824, stream);  // counts..scal
    k_transpose_z<<<dim3(32, 8, 16), 256, 0, stream>>>(z, zf, Ah);
    k_prep_w<<<4096, 256, 0, stream>>>(w, Bh, wnorm);
    k_sum_cs<<<64, 256, 0, stream>>>(cs, scal);
    k_gemm_argmin<<<dim3(128, STRIPS), 256, 0, stream>>>(Ah, Bh, wnorm, pout);
    k_select<<<4096, 256, 0, stream>>>(pout, zf, w, tokrank, counts, dmin);
    k_scan<<<1, 256, 0, stream>>>(counts, offsets);
    k_scatter<<<64, 256, 0, stream>>>(tokrank, offsets, perm);
    k_embed<<<4096, 256, 0, stream>>>(offsets, counts, perm, zf, ea, cs, scal,
                                      o_embed, o_cluster, o_wnew);
    k_write_out<<<dim3(32, 8, 16), 256, 0, stream>>>(tokrank, w, out);
    k_stats<<<64, 256, 0, stream>>>(counts, dmin, scal);
    k_scalars<<<1, 64, 0, stream>>>(scal, o_scal);
}